// Round 8
// baseline (153.728 us; speedup 1.0000x reference)
//
#include <hip/hip_runtime.h>

#define NPAIR  262144
#define BN_EPS 1e-5f
#define NBLK   256

typedef unsigned short u16;
typedef unsigned int   u32;
typedef __attribute__((ext_vector_type(8))) short bf16x8;
typedef __attribute__((ext_vector_type(4))) float f32x4;
typedef __attribute__((ext_vector_type(4))) unsigned short u16x4;
typedef __attribute__((ext_vector_type(4))) unsigned int u32x4;

__device__ __forceinline__ u16 f2bf(float f) {
    union { float f; unsigned u; } v; v.f = f;
    unsigned r = v.u + 0x7fffu + ((v.u >> 16) & 1u);
    return (u16)(r >> 16);
}
__device__ __forceinline__ float bf2f(u16 u) {
    union { unsigned u; float f; } v; v.u = ((unsigned)u) << 16; return v.f;
}
__device__ __forceinline__ u16x4 cvt4(float4 v) {
    u16x4 r;
    r[0] = f2bf(v.x); r[1] = f2bf(v.y); r[2] = f2bf(v.z); r[3] = f2bf(v.w);
    return r;
}
__device__ __forceinline__ bf16x8 cvt8_f32(const float* p) {
    f32x4 v0 = *(const f32x4*)p, v1 = *(const f32x4*)(p + 4);
    bf16x8 r;
    #pragma unroll
    for (int k = 0; k < 4; ++k) {
        r[k]     = (short)f2bf(v0[k]);
        r[4 + k] = (short)f2bf(v1[k]);
    }
    return r;
}
// LDS bf16 + BN + lrelu -> bf16 fragment
__device__ __forceinline__ bf16x8 cvt8_bn_lds(const u16* p, const float* a, const float* d) {
    u16x4 v0 = *(const u16x4*)p, v1 = *(const u16x4*)(p + 4);
    f32x4 a0 = *(const f32x4*)a, a1 = *(const f32x4*)(a + 4);
    f32x4 d0 = *(const f32x4*)d, d1 = *(const f32x4*)(d + 4);
    bf16x8 r;
    #pragma unroll
    for (int k = 0; k < 4; ++k) {
        float x0 = fmaf(a0[k], bf2f(v0[k]), d0[k]); x0 = fmaxf(x0, 0.01f * x0);
        float x1 = fmaf(a1[k], bf2f(v1[k]), d1[k]); x1 = fmaxf(x1, 0.01f * x1);
        r[k]     = (short)f2bf(x0);
        r[4 + k] = (short)f2bf(x1);
    }
    return r;
}

// grid barrier: sense-reversing, counters pre-zeroed by prep kernel.
__device__ __forceinline__ void gridbar(u32* cnt, u32* gen) {
    __syncthreads();
    __threadfence();
    if (threadIdx.x == 0) {
        const u32 g = __hip_atomic_load(gen, __ATOMIC_ACQUIRE, __HIP_MEMORY_SCOPE_AGENT);
        const u32 old = __hip_atomic_fetch_add(cnt, 1, __ATOMIC_ACQ_REL, __HIP_MEMORY_SCOPE_AGENT);
        if (old == NBLK - 1) {
            __hip_atomic_store(cnt, 0, __ATOMIC_RELEASE, __HIP_MEMORY_SCOPE_AGENT);
            __hip_atomic_fetch_add(gen, 1, __ATOMIC_ACQ_REL, __HIP_MEMORY_SCOPE_AGENT);
        } else {
            while (__hip_atomic_load(gen, __ATOMIC_ACQUIRE, __HIP_MEMORY_SCOPE_AGENT) == g) {}
        }
    }
    __syncthreads();
}

// ---------------------------------------------------------------------------
// prep: weight conversion + zero sums + zero barrier counters.
// ---------------------------------------------------------------------------
__global__ __launch_bounds__(256) void prep_kernel(
    const float* __restrict__ w1, const float4* __restrict__ w2,
    const float4* __restrict__ fw1, const float4* __restrict__ fw2,
    u16x4* __restrict__ W1b, u16x4* __restrict__ W2b,
    u16x4* __restrict__ FW1b, u16x4* __restrict__ FW2b,
    f32x4* __restrict__ sums4, u32* __restrict__ bar)
{
    int g = blockIdx.x * 256 + threadIdx.x;
    if (g < 16384) {   // W1b remap [512][128]
        const int o = g * 4, n = o >> 7, k = o & 127;
        const float4 v = *(const float4*)(w1 + (n < 256 ? n * 256 + k
                                                        : (n - 256) * 256 + 128 + k));
        W1b[g] = cvt4(v); return;
    }
    g -= 16384;
    if (g < 8192)  { W2b[g]  = cvt4(w2[g]);  return; }
    g -= 8192;
    if (g < 16384) { FW1b[g] = cvt4(fw1[g]); return; }
    g -= 16384;
    if (g < 8192)  { FW2b[g] = cvt4(fw2[g]); return; }
    g -= 8192;
    if (g < 272)   { const f32x4 z = {}; sums4[g] = z; return; }
    if (g == 272)  { bar[0] = 0; bar[1] = 0; bar[2] = 0; bar[3] = 0; }
}

// ---------------------------------------------------------------------------
// Persistent megakernel: one block per batch, 512 threads (8 waves).
// Phase B: PQ GEMM (f32 -> LDS), edge lists, EQ (regs) + analytic BN1 moments.
// [grid barrier]  Phase C: S (abs-split) -> agg MFMA -> H2 MFMA + BN2 stats.
// [grid barrier]  Phase D: out = lrelu(BN2(H2)) @ fw2^T + fb2.
// ---------------------------------------------------------------------------
__global__ __launch_bounds__(512, 2) void mega_kernel(
    const float* __restrict__ state, const float* __restrict__ edges,
    const float* __restrict__ b1, const float* __restrict__ g1,
    const float* __restrict__ be1, const float* __restrict__ b2,
    const float* __restrict__ fb1, const float* __restrict__ g2,
    const float* __restrict__ be2, const float* __restrict__ fb2,
    const u16* __restrict__ W1b, const u16* __restrict__ W2b,
    const u16* __restrict__ FW1b, const u16* __restrict__ FW2b,
    float* __restrict__ sums, u32* __restrict__ bar,
    float* __restrict__ out)
{
    __shared__ float Pf[32 * 256];                     // 32 KB
    __shared__ float Qf[33 * 256];                     // 33 KB (row 32 = 0)
    __shared__ u16 Asb[32 * 128];                      // 8 KB  (swizzled)
    __shared__ __align__(16) char pool[24576];         // Ssb+aggs | redA+redB
    __shared__ u16 H2s[32 * 256];                      // 16 KB (swizzled)
    __shared__ __align__(16) unsigned char list8[32 * 32];
    __shared__ u32 masks[32];
    __shared__ float cdf[32];
    __shared__ float sred[512];
    __shared__ float adl[512];

    const int b    = blockIdx.x;
    const int t    = threadIdx.x;
    const int lane = t & 63;
    const int w    = t >> 6;        // 0..7
    const int lr   = lane & 15;
    const int lkg  = lane >> 4;     // 0..3
    const int lk   = lkg * 8;
    const int c0   = lane * 4;

    // ---------------- Phase B ----------------
    if (t < 256) ((u32*)list8)[t] = 0x20202020u;       // pad sentinel j=32
    if (t < 64) { const f32x4 z = {}; *(f32x4*)&Qf[32 * 256 + t * 4] = z; }

    const int il0 = t >> 5;          // 0..15
    const int jt  = t & 31;
    const float ev0 = edges[(size_t)b * 1024 + il0 * 32 + jt];
    const float ev1 = edges[(size_t)b * 1024 + (il0 + 16) * 32 + jt];

    // PQ GEMM: wave w -> cols w*64..w*64+63; C kept f32 in LDS.
    {
        const int col0 = w * 64;
        f32x4 acc[2][4] = {};
        #pragma unroll
        for (int ks = 0; ks < 4; ++ks) {
            const int kabs = ks * 32 + lk;
            bf16x8 af[2];
            #pragma unroll
            for (int rf = 0; rf < 2; ++rf) {
                af[rf] = cvt8_f32(state + (size_t)(b * 32 + rf * 16 + lr) * 128 + kabs);
                if (w == 0) {
                    const int row = rf * 16 + lr;
                    *(bf16x8*)((char*)Asb + ((row * 256 + kabs * 2) ^ ((row & 7) << 4))) = af[rf];
                }
            }
            #pragma unroll
            for (int cf = 0; cf < 4; ++cf) {
                const bf16x8 bfr = *(const bf16x8*)(W1b + (size_t)(col0 + cf * 16 + lr) * 128 + kabs);
                #pragma unroll
                for (int rf = 0; rf < 2; ++rf)
                    acc[rf][cf] = __builtin_amdgcn_mfma_f32_16x16x32_bf16(af[rf], bfr, acc[rf][cf], 0, 0, 0);
            }
        }
        #pragma unroll
        for (int rf = 0; rf < 2; ++rf)
            #pragma unroll
            for (int cf = 0; cf < 4; ++cf) {
                const int col = col0 + cf * 16 + lr;
                #pragma unroll
                for (int r = 0; r < 4; ++r) {
                    const int row = rf * 16 + lkg * 4 + r;
                    const float v = acc[rf][cf][r];
                    if (col < 256) Pf[row * 256 + col] = v;
                    else           Qf[row * 256 + (col - 256)] = v;
                }
            }
    }
    __syncthreads();   // GEMM stores + inits visible

    // edge masks + compacted lists (lanes<32 -> row 2w / il0, lanes>=32 -> il0)
    {
        const unsigned long long bal0 = __ballot(ev0 != 0.f);
        const u32 m0 = (lane < 32) ? (u32)bal0 : (u32)(bal0 >> 32);
        if (ev0 != 0.f)
            list8[il0 * 32 + __popc(m0 & ((1u << jt) - 1u))] = (unsigned char)jt;
        if (jt == 0) masks[il0] = m0;
        const unsigned long long bal1 = __ballot(ev1 != 0.f);
        const u32 m1 = (lane < 32) ? (u32)bal1 : (u32)(bal1 >> 32);
        if (ev1 != 0.f)
            list8[(il0 + 16) * 32 + __popc(m1 & ((1u << jt) - 1u))] = (unsigned char)jt;
        if (jt == 0) masks[il0 + 16] = m1;
    }
    __syncthreads();   // masks + lists ready

    if (t < 32) {
        u32 cnt = 0;
        #pragma unroll
        for (int i = 0; i < 32; ++i) cnt += (masks[i] >> t) & 1u;
        cdf[t] = (float)cnt;
    }
    if (t == 0) {
        int tot = 0;
        #pragma unroll
        for (int i = 0; i < 32; ++i) tot += __popc(masks[i]);
        atomicAdd(&sums[512], (float)tot);
    }

    const f32x4 b14 = *(const f32x4*)(b1 + c0);
    f32x4 eqr[4];                       // EQ kept in registers for phase C
    f32x4 sumA = {}, sumB = {};

    #pragma unroll
    for (int ii = 0; ii < 4; ++ii) {    // wave w owns rows 4w..4w+3
        const int il = 4 * w + ii;
        const int n1 = __popc(masks[il]);
        const int npad = (n1 + 3) & ~3;
        f32x4 eq = {};
        const u32x4 l0 = *(const u32x4*)(list8 + il * 32);
        const u32x4 l1 = *(const u32x4*)(list8 + il * 32 + 16);
        const u32 wbuf[8] = {l0[0], l0[1], l0[2], l0[3], l1[0], l1[1], l1[2], l1[3]};
        #pragma unroll
        for (int wi = 0; wi < 8; ++wi) {
            if (wi * 4 >= npad) break;
            const u32 w4 = wbuf[wi];
            #pragma unroll
            for (int kb = 0; kb < 4; ++kb) {
                const int j = (w4 >> (kb * 8)) & 0xff;   // pads -> row 32 (zero)
                const f32x4 q = *(const f32x4*)&Qf[j * 256 + c0];
                #pragma unroll
                for (int k = 0; k < 4; ++k) eq[k] += q[k];
            }
        }
        eqr[ii] = eq;
        const f32x4 p4 = *(const f32x4*)&Pf[il * 256 + c0];
        const float frd = (float)n1;
        #pragma unroll
        for (int k = 0; k < 4; ++k) {
            const float pb = p4[k] + b14[k];
            sumA[k] += frd * pb + eq[k];
            sumB[k] = fmaf(frd * pb + 2.f * eq[k], pb, sumB[k]);
        }
    }
    __syncthreads();   // cdf settled; Qf reads for EQ done

    {
        float* redA = (float*)pool;
        float* redB = (float*)pool + 2048;
        #pragma unroll
        for (int jj = 0; jj < 4; ++jj) {   // coldeg-weighted Q^2, j = 4w..4w+3
            const int j = 4 * w + jj;
            const float cdj = cdf[j];
            const f32x4 q = *(const f32x4*)&Qf[j * 256 + c0];
            #pragma unroll
            for (int k = 0; k < 4; ++k) sumB[k] = fmaf(cdj * q[k], q[k], sumB[k]);
        }
        *(f32x4*)&redA[w * 256 + c0] = sumA;
        *(f32x4*)&redB[w * 256 + c0] = sumB;
        __syncthreads();
        if (t < 256) {
            float a = 0.f, bb = 0.f;
            #pragma unroll
            for (int ww = 0; ww < 8; ++ww) {
                a  += redA[ww * 256 + t];
                bb += redB[ww * 256 + t];
            }
            atomicAdd(&sums[t], a);
            atomicAdd(&sums[256 + t], bb);
        }
    }

    gridbar(&bar[0], &bar[1]);

    // ---------------- Phase C ----------------
    u16* Ssb  = (u16*)pool;             // 16 KB, swizzled
    u16* aggs = (u16*)(pool + 16384);   // 8 KB, swizzled

    const float Etot = sums[512];
    const float nzc  = (float)NPAIR - Etot;
    const float invN = 1.f / (float)NPAIR;
    const f32x4 s1  = *(const f32x4*)(sums + c0);
    const f32x4 s2  = *(const f32x4*)(sums + 256 + c0);
    const f32x4 g4  = *(const f32x4*)(g1 + c0);
    const f32x4 be4 = *(const f32x4*)(be1 + c0);
    f32x4 a4, d4, ld4;
    #pragma unroll
    for (int k = 0; k < 4; ++k) {
        const float mean = (s1[k] + nzc * b14[k]) * invN;
        const float ms   = (s2[k] + nzc * b14[k] * b14[k]) * invN;
        const float var  = fmaf(-mean, mean, ms);
        a4[k]  = g4[k] * rsqrtf(var + BN_EPS);
        d4[k]  = fmaf(b14[k] - mean, a4[k], be4[k]);
        ld4[k] = fmaxf(d4[k], 0.01f * d4[k]);
    }

    #pragma unroll
    for (int ii = 0; ii < 4; ++ii) {
        const int il = 4 * w + ii;
        const int n1 = __popc(masks[il]);
        const int npad = (n1 + 3) & ~3;
        const float frd = (float)n1;
        const float fz  = (float)(32 - n1);
        const float fp  = (float)(npad - n1);
        const f32x4 p4 = *(const f32x4*)&Pf[il * 256 + c0];
        f32x4 ap, absacc;
        #pragma unroll
        for (int k = 0; k < 4; ++k) {
            ap[k] = fmaf(a4[k], p4[k], d4[k]);
            absacc[k] = -fp * fabsf(ap[k]);        // pad correction
        }
        const u32x4 l0 = *(const u32x4*)(list8 + il * 32);
        const u32x4 l1 = *(const u32x4*)(list8 + il * 32 + 16);
        const u32 wbuf[8] = {l0[0], l0[1], l0[2], l0[3], l1[0], l1[1], l1[2], l1[3]};
        #pragma unroll
        for (int wi = 0; wi < 8; ++wi) {
            if (wi * 4 >= npad) break;
            const u32 w4 = wbuf[wi];
            #pragma unroll
            for (int kb = 0; kb < 4; ++kb) {
                const int j = (w4 >> (kb * 8)) & 0xff;
                const f32x4 q = *(const f32x4*)&Qf[j * 256 + c0];
                #pragma unroll
                for (int k = 0; k < 4; ++k)
                    absacc[k] += fabsf(fmaf(a4[k], q[k], ap[k]));
            }
        }
        u16x4 o;
        #pragma unroll
        for (int k = 0; k < 4; ++k) {
            const float lin = fmaf(frd, ap[k], a4[k] * eqr[ii][k]);
            const float S = fmaf(fz, ld4[k], fmaf(0.505f, lin, 0.495f * absacc[k]));
            o[k] = f2bf(S);
        }
        *(u16x4*)((char*)Ssb + il * 512 + ((lane * 8) ^ ((il & 7) << 4))) = o;
    }
    __syncthreads();

    // agg = S @ w2^T + 32*b2 -> aggs (bf16 LDS); wave w -> cols w*16..w*16+15
    {
        f32x4 acc2[2] = {};
        #pragma unroll
        for (int ks = 0; ks < 8; ++ks) {
            const bf16x8 bfr = *(const bf16x8*)(W2b + (size_t)(w * 16 + lr) * 256 + ks * 32 + lk);
            const int rdoff = ks * 64 + lkg * 16;
            #pragma unroll
            for (int rf = 0; rf < 2; ++rf) {
                const int row = rf * 16 + lr;
                const bf16x8 afr = *(const bf16x8*)((char*)Ssb + row * 512 + (rdoff ^ ((row & 7) << 4)));
                acc2[rf] = __builtin_amdgcn_mfma_f32_16x16x32_bf16(afr, bfr, acc2[rf], 0, 0, 0);
            }
        }
        const int col = w * 16 + lr;
        const float bv = 32.f * b2[col];
        #pragma unroll
        for (int rf = 0; rf < 2; ++rf)
            #pragma unroll
            for (int r = 0; r < 4; ++r) {
                const int row = rf * 16 + lkg * 4 + r;
                *(u16*)((char*)aggs + ((row * 256 + col * 2) ^ ((row & 7) << 4))) = f2bf(acc2[rf][r] + bv);
            }
    }
    sred[t] = 0.f;
    __syncthreads();

    // H2 = [Asb | aggs] @ fw1^T + fb1 -> H2s (bf16) + BN2 stats
    {
        f32x4 acc3[2][2] = {};
        #pragma unroll
        for (int ks = 0; ks < 8; ++ks) {
            const int kabs = ks * 32 + lk;
            bf16x8 af3[2];
            #pragma unroll
            for (int rf = 0; rf < 2; ++rf) {
                const int row = rf * 16 + lr;
                if (ks < 4)
                    af3[rf] = *(const bf16x8*)((char*)Asb + ((row * 256 + kabs * 2) ^ ((row & 7) << 4)));
                else
                    af3[rf] = *(const bf16x8*)((char*)aggs + ((row * 256 + (kabs - 128) * 2) ^ ((row & 7) << 4)));
            }
            #pragma unroll
            for (int cf = 0; cf < 2; ++cf) {
                const bf16x8 bfr = *(const bf16x8*)(FW1b + (size_t)(w * 32 + cf * 16 + lr) * 256 + kabs);
                #pragma unroll
                for (int rf = 0; rf < 2; ++rf)
                    acc3[rf][cf] = __builtin_amdgcn_mfma_f32_16x16x32_bf16(af3[rf], bfr, acc3[rf][cf], 0, 0, 0);
            }
        }
        #pragma unroll
        for (int cf = 0; cf < 2; ++cf) {
            const int col = w * 32 + cf * 16 + lr;
            const float bv = fb1[col];
            float s = 0.f, ss = 0.f;
            #pragma unroll
            for (int rf = 0; rf < 2; ++rf)
                #pragma unroll
                for (int r = 0; r < 4; ++r) {
                    const int row = rf * 16 + lkg * 4 + r;
                    const float v = acc3[rf][cf][r] + bv;
                    *(u16*)((char*)H2s + ((row * 512 + col * 2) ^ ((row & 7) << 4))) = f2bf(v);
                    s += v;
                    ss = fmaf(v, v, ss);
                }
            atomicAdd(&sred[col], s);
            atomicAdd(&sred[256 + col], ss);
        }
    }
    __syncthreads();
    if (t < 256) {
        atomicAdd(&sums[544 + t], sred[t]);
        atomicAdd(&sums[544 + 256 + t], sred[256 + t]);
    }

    gridbar(&bar[2], &bar[3]);

    // ---------------- Phase D ----------------
    if (t < 256) {
        const float invR = 1.f / 8192.f;
        const float mean = sums[544 + t] * invR;
        const float var  = fmaf(-mean, mean, sums[544 + 256 + t] * invR);
        const float a    = g2[t] * rsqrtf(var + BN_EPS);
        adl[t]       = a;
        adl[256 + t] = fmaf(-mean, a, be2[t]);
    }
    __syncthreads();

    {
        f32x4 acc4[2] = {};
        #pragma unroll
        for (int ks = 0; ks < 8; ++ks) {
            const int kabs = ks * 32 + lk;
            const bf16x8 bfr = *(const bf16x8*)(FW2b + (size_t)(w * 16 + lr) * 256 + kabs);
            #pragma unroll
            for (int rf = 0; rf < 2; ++rf) {
                const int row = rf * 16 + lr;
                const u16* hp = (const u16*)((char*)H2s + ((row * 512 + kabs * 2) ^ ((row & 7) << 4)));
                const bf16x8 af4 = cvt8_bn_lds(hp, adl + kabs, adl + 256 + kabs);
                acc4[rf] = __builtin_amdgcn_mfma_f32_16x16x32_bf16(af4, bfr, acc4[rf], 0, 0, 0);
            }
        }
        const int col = w * 16 + lr;
        const float bv = fb2[col];
        #pragma unroll
        for (int rf = 0; rf < 2; ++rf)
            #pragma unroll
            for (int r = 0; r < 4; ++r) {
                const int row = rf * 16 + lkg * 4 + r;
                out[(size_t)(b * 32 + row) * 128 + col] = acc4[rf][r] + bv;
            }
    }
}

// ---------------------------------------------------------------------------
extern "C" void kernel_launch(void* const* d_in, const int* in_sizes, int n_in,
                              void* d_out, int out_size, void* d_ws, size_t ws_size,
                              hipStream_t stream)
{
    const float* state     = (const float*)d_in[0];
    const float* edges     = (const float*)d_in[1];
    const float* msg_w1    = (const float*)d_in[2];
    const float* msg_b1    = (const float*)d_in[3];
    const float* msg_gamma = (const float*)d_in[4];
    const float* msg_beta  = (const float*)d_in[5];
    const float* msg_w2    = (const float*)d_in[6];
    const float* msg_b2    = (const float*)d_in[7];
    const float* fin_w1    = (const float*)d_in[8];
    const float* fin_b1    = (const float*)d_in[9];
    const float* fin_gamma = (const float*)d_in[10];
    const float* fin_beta  = (const float*)d_in[11];
    const float* fin_w2    = (const float*)d_in[12];
    const float* fin_b2    = (const float*)d_in[13];

    char* w = (char*)d_ws;
    u16*   W1b  = (u16*)(w);              // [512][128] bf16   128 KB
    u16*   W2b  = (u16*)(w + 131072);     // [128][256] bf16    64 KB
    u16*   FW1b = (u16*)(w + 196608);     // [256][256] bf16   128 KB
    u16*   FW2b = (u16*)(w + 327680);     // [128][256] bf16    64 KB
    float* sums = (float*)(w + 393216);   // [0..511] s1, [512] Etot, [544..1055] s2
    u32*   bar  = (u32*)(w + 397568);     // 4 barrier words

    prep_kernel<<<256, 256, 0, stream>>>(
        msg_w1, (const float4*)msg_w2, (const float4*)fin_w1, (const float4*)fin_w2,
        (u16x4*)W1b, (u16x4*)W2b, (u16x4*)FW1b, (u16x4*)FW2b,
        (f32x4*)sums, bar);

    mega_kernel<<<NBLK, 512, 0, stream>>>(
        state, edges, msg_b1, msg_gamma, msg_beta, msg_b2,
        fin_b1, fin_gamma, fin_beta, fin_b2,
        W1b, W2b, FW1b, FW2b, sums, bar, (float*)d_out);
}

// Round 9
// 82.929 us; speedup vs baseline: 1.8537x; 1.8537x over previous
//
#include <hip/hip_runtime.h>

#define NPAIR  262144
#define BN_EPS 1e-5f

typedef unsigned short u16;
typedef unsigned int   u32;
typedef __attribute__((ext_vector_type(8))) short bf16x8;
typedef __attribute__((ext_vector_type(4))) float f32x4;
typedef __attribute__((ext_vector_type(4))) unsigned short u16x4;
typedef __attribute__((ext_vector_type(4))) unsigned int u32x4;

__device__ __forceinline__ u16 f2bf(float f) {
    union { float f; unsigned u; } v; v.f = f;
    unsigned r = v.u + 0x7fffu + ((v.u >> 16) & 1u);
    return (u16)(r >> 16);
}
__device__ __forceinline__ float bf2f(u16 u) {
    union { unsigned u; float f; } v; v.u = ((unsigned)u) << 16; return v.f;
}
__device__ __forceinline__ bf16x8 cvt8_f32(const float* p) {
    f32x4 v0 = *(const f32x4*)p, v1 = *(const f32x4*)(p + 4);
    bf16x8 r;
    #pragma unroll
    for (int k = 0; k < 4; ++k) {
        r[k]     = (short)f2bf(v0[k]);
        r[4 + k] = (short)f2bf(v1[k]);
    }
    return r;
}
// bf16 input + BN + lrelu -> bf16 fragment
__device__ __forceinline__ bf16x8 cvt8_bn_b(const u16* p, const float* a, const float* d) {
    u16x4 v0 = *(const u16x4*)p, v1 = *(const u16x4*)(p + 4);
    f32x4 a0 = *(const f32x4*)a, a1 = *(const f32x4*)(a + 4);
    f32x4 d0 = *(const f32x4*)d, d1 = *(const f32x4*)(d + 4);
    bf16x8 r;
    #pragma unroll
    for (int k = 0; k < 4; ++k) {
        float x0 = fmaf(a0[k], bf2f(v0[k]), d0[k]); x0 = fmaxf(x0, 0.01f * x0);
        float x1 = fmaf(a1[k], bf2f(v1[k]), d1[k]); x1 = fmaxf(x1, 0.01f * x1);
        r[k]     = (short)f2bf(x0);
        r[4 + k] = (short)f2bf(x1);
    }
    return r;
}

// ---------------------------------------------------------------------------
// Per-batch fused kernel, 1024 threads (16 waves):
//   PQ[32x512] = state @ [w1a|w1b]^T (MFMA, 32 cols/wave, W1 cvt inline)
//   -> PQb bf16 ;  EQ_i = sum_{j:e=1} Q_j -> EQf ;  analytic BN1 moments.
// ---------------------------------------------------------------------------
__global__ __launch_bounds__(1024) void pq_stats(
    const float* __restrict__ state, const float* __restrict__ w1,
    const float* __restrict__ edges, const float* __restrict__ b1,
    u16* __restrict__ PQb, float* __restrict__ EQf,
    float* __restrict__ sums)
{
    __shared__ float Qls[33 * 256];                 // 33 KB rounded Q (row32=0)
    __shared__ float redA[16 * 256];                // 16 KB
    __shared__ float redB[16 * 256];                // 16 KB
    __shared__ u32 masks[32];
    __shared__ __align__(16) unsigned char list8[32 * 32];
    __shared__ float cdf[32];

    const int b    = blockIdx.x;
    const int t    = threadIdx.x;
    const int lane = t & 63;
    const int w    = t >> 6;       // 0..15
    const int lr   = lane & 15;
    const int lk   = (lane >> 4) * 8;
    const int c0   = lane * 4;

    if (t < 256) ((u32*)list8)[t] = 0x20202020u;    // pad sentinel j=32
    if (t < 64) { const f32x4 z = {}; *(f32x4*)&Qls[32 * 256 + t * 4] = z; }

    // one edge per thread (t = il*32 + j)
    const float ev = edges[(size_t)b * 1024 + t];

    // ---- GEMM: wave w covers cols w*32..w*32+31 (W1 converted inline) ----
    const int col0 = w * 32;
    f32x4 acc[2][2] = {};
    #pragma unroll
    for (int ks = 0; ks < 4; ++ks) {
        const int kabs = ks * 32 + lk;
        bf16x8 af[2];
        #pragma unroll
        for (int rf = 0; rf < 2; ++rf)
            af[rf] = cvt8_f32(state + (size_t)(b * 32 + rf * 16 + lr) * 128 + kabs);
        #pragma unroll
        for (int cf = 0; cf < 2; ++cf) {
            const int coln = col0 + cf * 16 + lr;
            const float* wp = (coln < 256) ? (w1 + (size_t)coln * 256 + kabs)
                                           : (w1 + (size_t)(coln - 256) * 256 + 128 + kabs);
            const bf16x8 bfr = cvt8_f32(wp);
            #pragma unroll
            for (int rf = 0; rf < 2; ++rf)
                acc[rf][cf] = __builtin_amdgcn_mfma_f32_16x16x32_bf16(af[rf], bfr, acc[rf][cf], 0, 0, 0);
        }
    }
    #pragma unroll
    for (int rf = 0; rf < 2; ++rf)
        #pragma unroll
        for (int cf = 0; cf < 2; ++cf) {
            const int col = col0 + cf * 16 + lr;
            #pragma unroll
            for (int r = 0; r < 4; ++r) {
                const int row = rf * 16 + (lane >> 4) * 4 + r;
                const u16 u = f2bf(acc[rf][cf][r]);
                PQb[(size_t)(b * 32 + row) * 512 + col] = u;
                if (col >= 256) Qls[row * 256 + (col - 256)] = bf2f(u);
            }
        }
    __syncthreads();   // S1: staging + inits visible

    // ---- masks + compacted lists ----
    {
        const int il_t = t >> 5;
        const int j_t  = t & 31;
        const unsigned long long bal = __ballot(ev != 0.f);
        const u32 m32 = (lane < 32) ? (u32)bal : (u32)(bal >> 32);
        if (ev != 0.f)
            list8[il_t * 32 + __popc(m32 & ((1u << j_t) - 1u))] = (unsigned char)j_t;
        if (j_t == 0) masks[il_t] = m32;
    }
    __syncthreads();   // S2: masks + lists ready

    if (t < 32) {
        u32 cnt = 0;
        #pragma unroll
        for (int i = 0; i < 32; ++i) cnt += (masks[i] >> t) & 1u;
        cdf[t] = (float)cnt;
    }
    if (t == 0) {
        int tot = 0;
        #pragma unroll
        for (int i = 0; i < 32; ++i) tot += __popc(masks[i]);
        atomicAdd(&sums[512], (float)tot);
    }

    const f32x4 b14 = *(const f32x4*)(b1 + c0);
    f32x4 sumA = {}, sumB = {};

    // ---- EQ + row-terms: wave w owns rows 2w, 2w+1 ----
    #pragma unroll
    for (int ii = 0; ii < 2; ++ii) {
        const int il = 2 * w + ii;
        const int n1 = __popc(masks[il]);
        const int npad = (n1 + 3) & ~3;
        const float frd = (float)n1;
        f32x4 eq = {};
        const u32x4 l0 = *(const u32x4*)(list8 + il * 32);
        const u32x4 l1 = *(const u32x4*)(list8 + il * 32 + 16);
        const u32 wbuf[8] = {l0[0], l0[1], l0[2], l0[3], l1[0], l1[1], l1[2], l1[3]};
        #pragma unroll
        for (int wi = 0; wi < 8; ++wi) {
            if (wi * 4 >= npad) break;
            const u32 w4 = wbuf[wi];
            #pragma unroll
            for (int kb = 0; kb < 4; ++kb) {
                const int j = (w4 >> (kb * 8)) & 0xff;          // pads -> row 32 (zero)
                const f32x4 q = *(const f32x4*)&Qls[j * 256 + c0];
                #pragma unroll
                for (int k = 0; k < 4; ++k) eq[k] += q[k];
            }
        }
        *(f32x4*)(EQf + (size_t)(b * 32 + il) * 256 + c0) = eq;
        const u16x4 pu = *(const u16x4*)(PQb + (size_t)(b * 32 + il) * 512 + c0);
        #pragma unroll
        for (int k = 0; k < 4; ++k) {
            const float pb = bf2f(pu[k]) + b14[k];
            sumA[k] += frd * pb + eq[k];
            sumB[k] = fmaf(frd * pb + 2.f * eq[k], pb, sumB[k]);
        }
    }
    __syncthreads();   // S3: cdf ready

    // ---- coldeg-weighted Q^2: wave w uses j = 2w, 2w+1 ----
    #pragma unroll
    for (int jj = 0; jj < 2; ++jj) {
        const int j = 2 * w + jj;
        const float cdj = cdf[j];
        const f32x4 q = *(const f32x4*)&Qls[j * 256 + c0];
        #pragma unroll
        for (int k = 0; k < 4; ++k) sumB[k] = fmaf(cdj * q[k], q[k], sumB[k]);
    }
    *(f32x4*)&redA[w * 256 + c0] = sumA;
    *(f32x4*)&redB[w * 256 + c0] = sumB;
    __syncthreads();   // S4
    if (t < 256) {
        float a = 0.f, bb = 0.f;
        #pragma unroll
        for (int ww = 0; ww < 16; ++ww) {
            a  += redA[ww * 256 + t];
            bb += redB[ww * 256 + t];
        }
        atomicAdd(&sums[t], a);
        atomicAdd(&sums[256 + t], bb);
    }
}

// ---------------------------------------------------------------------------
// S (abs-split) -> agg MFMA (LDS) -> H2 MFMA + BN2 stats, all batch-local.
// 512 threads (8 waves), 16 rows/block, grid (256, 2).
// ---------------------------------------------------------------------------
__global__ __launch_bounds__(512) void s_agg_h2_kernel(
    const u16* __restrict__ PQb, const float* __restrict__ edges,
    const float* __restrict__ EQf, const float* __restrict__ sums,
    const float* __restrict__ gamma, const float* __restrict__ beta,
    const float* __restrict__ b1, const float* __restrict__ state,
    const float* __restrict__ w2, const float* __restrict__ b2,
    const float* __restrict__ fw1, const float* __restrict__ fb1,
    u16* __restrict__ H2b, float* __restrict__ sums2)
{
    __shared__ float Qls[33 * 256];               // 33 KB a-scaled Q (row32=0)
    __shared__ u16 Ssb[16 * 256];                 // 8 KB, swizzled
    __shared__ u16 Asb[16 * 128];                 // 4 KB, swizzled (state bf16)
    __shared__ u16 aggs[16 * 128];                // 4 KB, swizzled
    __shared__ __align__(16) unsigned char list8[16 * 32];
    __shared__ int n1s[16];
    __shared__ float sred[512];

    const int b    = blockIdx.x;
    const int i0   = blockIdx.y * 16;
    const int t    = threadIdx.x;
    const int lane = t & 63;
    const int w    = t >> 6;      // 0..7
    const int lr   = lane & 15;
    const int lkg  = lane >> 4;   // 0..3
    const int lk   = lkg * 8;
    const int c0   = lane * 4;

    sred[t] = 0.f;

    // BN1 coefficients from analytic sums
    const float Etot = sums[512];
    const float nz   = (float)NPAIR - Etot;
    const float invN = 1.f / (float)NPAIR;
    const f32x4 s1  = *(const f32x4*)(sums + c0);
    const f32x4 s2  = *(const f32x4*)(sums + 256 + c0);
    const f32x4 g4  = *(const f32x4*)(gamma + c0);
    const f32x4 be4 = *(const f32x4*)(beta + c0);
    const f32x4 b14 = *(const f32x4*)(b1 + c0);
    f32x4 a4, d4, ld4;
    #pragma unroll
    for (int k = 0; k < 4; ++k) {
        const float mean = (s1[k] + nz * b14[k]) * invN;
        const float ms   = (s2[k] + nz * b14[k] * b14[k]) * invN;
        const float var  = fmaf(-mean, mean, ms);
        a4[k]  = g4[k] * rsqrtf(var + BN_EPS);
        d4[k]  = fmaf(b14[k] - mean, a4[k], be4[k]);
        ld4[k] = fmaxf(d4[k], 0.01f * d4[k]);
    }

    // stage a-scaled Q (f32): 8 waves x 4 iters = 32 rows
    #pragma unroll
    for (int it = 0; it < 4; ++it) {
        const int row = w + it * 8;
        const u16x4 qu = *(const u16x4*)(PQb + (size_t)(b * 32 + row) * 512 + 256 + c0);
        f32x4 q;
        #pragma unroll
        for (int k = 0; k < 4; ++k) q[k] = a4[k] * bf2f(qu[k]);
        *(f32x4*)&Qls[row * 256 + c0] = q;
    }
    // stage state rows (bf16, swizzled) for the H2 GEMM
    if (t < 256) {
        const int row = t >> 4, k8 = (t & 15) * 8;
        const bf16x8 av = cvt8_f32(state + (size_t)(b * 32 + i0 + row) * 128 + k8);
        *(bf16x8*)((char*)Asb + ((row * 256 + k8 * 2) ^ ((row & 7) << 4))) = av;
    }
    if (t < 64) { const f32x4 z = {}; *(f32x4*)&Qls[32 * 256 + t * 4] = z; }
    if (t < 128) ((u32*)list8)[t] = 0x20202020u;

    const float ev = edges[(size_t)b * 1024 + (i0 + (t >> 5)) * 32 + (t & 31)];
    __syncthreads();

    {
        const int il_t = t >> 5;
        const int j_t  = t & 31;
        const unsigned long long bal = __ballot(ev != 0.f);
        const u32 m32 = (lane < 32) ? (u32)bal : (u32)(bal >> 32);
        if (ev != 0.f)
            list8[il_t * 32 + __popc(m32 & ((1u << j_t) - 1u))] = (unsigned char)j_t;
        if (j_t == 0) n1s[il_t] = __popc(m32);
    }
    __syncthreads();

    // ---- S rows (abs-split), wave w owns rows 2w, 2w+1 ----
    #pragma unroll
    for (int ii = 0; ii < 2; ++ii) {
        const int il = 2 * w + ii;
        const int gi = b * 32 + i0 + il;
        const int n1 = n1s[il];
        const int npad = (n1 + 3) & ~3;
        const float frd = (float)n1;
        const float fz = (float)(32 - n1);
        const float fp = (float)(npad - n1);
        const u16x4 pu = *(const u16x4*)(PQb + (size_t)gi * 512 + c0);
        const f32x4 eq4 = *(const f32x4*)(EQf + (size_t)gi * 256 + c0);
        f32x4 ap, absacc;
        #pragma unroll
        for (int k = 0; k < 4; ++k) {
            ap[k] = fmaf(a4[k], bf2f(pu[k]), d4[k]);
            absacc[k] = -fp * fabsf(ap[k]);      // pad correction
        }
        const u32x4 l0 = *(const u32x4*)(list8 + il * 32);
        const u32x4 l1 = *(const u32x4*)(list8 + il * 32 + 16);
        const u32 wbuf[8] = {l0[0], l0[1], l0[2], l0[3], l1[0], l1[1], l1[2], l1[3]};
        #pragma unroll
        for (int wi = 0; wi < 8; ++wi) {
            if (wi * 4 >= npad) break;
            const u32 w4 = wbuf[wi];
            #pragma unroll
            for (int kb = 0; kb < 4; ++kb) {
                const int j = (w4 >> (kb * 8)) & 0xff;
                const f32x4 q = *(const f32x4*)&Qls[j * 256 + c0];
                #pragma unroll
                for (int k = 0; k < 4; ++k)
                    absacc[k] += fabsf(ap[k] + q[k]);
            }
        }
        u16x4 o;
        #pragma unroll
        for (int k = 0; k < 4; ++k) {
            const float lin = fmaf(frd, ap[k], a4[k] * eq4[k]);
            const float S = fmaf(fz, ld4[k], fmaf(0.505f, lin, 0.495f * absacc[k]));
            o[k] = f2bf(S);
        }
        *(u16x4*)((char*)Ssb + il * 512 + ((lane * 8) ^ ((il & 7) << 4))) = o;
    }
    __syncthreads();

    // ---- agg = S @ w2^T + 32*b2 -> aggs LDS (w2 cvt inline) ----
    {
        f32x4 acc2 = {};
        #pragma unroll
        for (int ks = 0; ks < 8; ++ks) {
            const int rdoff = (ks * 64 + lkg * 16) ^ ((lr & 7) << 4);
            const bf16x8 afr = *(const bf16x8*)((const char*)Ssb + lr * 512 + rdoff);
            const bf16x8 bfr = cvt8_f32(w2 + (size_t)(w * 16 + lr) * 256 + ks * 32 + lk);
            acc2 = __builtin_amdgcn_mfma_f32_16x16x32_bf16(afr, bfr, acc2, 0, 0, 0);
        }
        const int col = w * 16 + lr;
        const float bv = 32.f * b2[col];
        #pragma unroll
        for (int r = 0; r < 4; ++r) {
            const int row = lkg * 4 + r;
            *(u16*)((char*)aggs + ((row * 256 + col * 2) ^ ((row & 7) << 4))) = f2bf(acc2[r] + bv);
        }
    }
    __syncthreads();

    // ---- H2 = [Asb | aggs] @ fw1^T + fb1 -> H2b global + BN2 stats ----
    {
        f32x4 acc3[2] = {};
        #pragma unroll
        for (int ks = 0; ks < 8; ++ks) {
            const int kabs = ks * 32 + lk;
            const int row = lr;
            bf16x8 af3;
            if (ks < 4)
                af3 = *(const bf16x8*)((const char*)Asb + ((row * 256 + kabs * 2) ^ ((row & 7) << 4)));
            else
                af3 = *(const bf16x8*)((const char*)aggs + ((row * 256 + (kabs - 128) * 2) ^ ((row & 7) << 4)));
            #pragma unroll
            for (int cf = 0; cf < 2; ++cf) {
                const int col = w * 32 + cf * 16 + lr;
                const bf16x8 bfr = cvt8_f32(fw1 + (size_t)col * 256 + kabs);
                acc3[cf] = __builtin_amdgcn_mfma_f32_16x16x32_bf16(af3, bfr, acc3[cf], 0, 0, 0);
            }
        }
        #pragma unroll
        for (int cf = 0; cf < 2; ++cf) {
            const int col = w * 32 + cf * 16 + lr;
            const float bv = fb1[col];
            float s = 0.f, ss = 0.f;
            #pragma unroll
            for (int r = 0; r < 4; ++r) {
                const int row = lkg * 4 + r;
                const float v = acc3[cf][r] + bv;
                H2b[(size_t)(b * 32 + i0 + row) * 256 + col] = f2bf(v);
                s += v;
                ss = fmaf(v, v, ss);
            }
            atomicAdd(&sred[col], s);
            atomicAdd(&sred[256 + col], ss);
        }
    }
    __syncthreads();
    if (t < 256) {
        atomicAdd(&sums2[t], sred[t]);
        atomicAdd(&sums2[256 + t], sred[256 + t]);
    }
}

// ---------------------------------------------------------------------------
// out = lrelu(bn(H2b)) @ fw2^T + fb2, finalize2 in-block, fw2 cvt inline.
// ---------------------------------------------------------------------------
__global__ __launch_bounds__(256) void out_gemm(
    const u16* __restrict__ H2b, const float* __restrict__ fw2,
    const float* __restrict__ fb2, const float* __restrict__ sums2,
    const float* __restrict__ gamma, const float* __restrict__ beta,
    float* __restrict__ out)
{
    __shared__ float adl[512];
    const int t = threadIdx.x;
    {
        const float invR = 1.f / 8192.f;
        const float mean = sums2[t] * invR;
        const float var  = fmaf(-mean, mean, sums2[256 + t] * invR);
        const float a    = gamma[t] * rsqrtf(var + BN_EPS);
        adl[t]       = a;
        adl[256 + t] = fmaf(-mean, a, beta[t]);
    }
    __syncthreads();

    const int lane = t & 63;
    const int wave = t >> 6;
    const int row0 = blockIdx.y * 64 + wave * 16;
    const int col0 = blockIdx.x * 32;
    const int lr = lane & 15;
    const int lk = (lane >> 4) * 8;

    f32x4 acc[2] = {};
    #pragma unroll
    for (int ks = 0; ks < 8; ++ks) {
        const int kabs = ks * 32 + lk;
        const bf16x8 af = cvt8_bn_b(H2b + (size_t)(row0 + lr) * 256 + kabs,
                                    adl + kabs, adl + 256 + kabs);
        #pragma unroll
        for (int cf = 0; cf < 2; ++cf) {
            const bf16x8 bf = cvt8_f32(fw2 + (size_t)(col0 + cf * 16 + lr) * 256 + kabs);
            acc[cf] = __builtin_amdgcn_mfma_f32_16x16x32_bf16(af, bf, acc[cf], 0, 0, 0);
        }
    }
    #pragma unroll
    for (int cf = 0; cf < 2; ++cf) {
        const int col = col0 + cf * 16 + lr;
        const float bv = fb2[col];
        #pragma unroll
        for (int r = 0; r < 4; ++r) {
            const int row = row0 + (lane >> 4) * 4 + r;
            out[(size_t)row * 128 + col] = acc[cf][r] + bv;
        }
    }
}

// ---------------------------------------------------------------------------
extern "C" void kernel_launch(void* const* d_in, const int* in_sizes, int n_in,
                              void* d_out, int out_size, void* d_ws, size_t ws_size,
                              hipStream_t stream)
{
    const float* state     = (const float*)d_in[0];
    const float* edges     = (const float*)d_in[1];
    const float* msg_w1    = (const float*)d_in[2];
    const float* msg_b1    = (const float*)d_in[3];
    const float* msg_gamma = (const float*)d_in[4];
    const float* msg_beta  = (const float*)d_in[5];
    const float* msg_w2    = (const float*)d_in[6];
    const float* msg_b2    = (const float*)d_in[7];
    const float* fin_w1    = (const float*)d_in[8];
    const float* fin_b1    = (const float*)d_in[9];
    const float* fin_gamma = (const float*)d_in[10];
    const float* fin_beta  = (const float*)d_in[11];
    const float* fin_w2    = (const float*)d_in[12];
    const float* fin_b2    = (const float*)d_in[13];

    char* w = (char*)d_ws;
    u16*   PQb  = (u16*)(w);                // 8192x512 bf16  ( 8 MB)
    float* EQf  = (float*)(w + 8388608);    // 8192x256 f32   ( 8 MB)
    u16*   H2b  = (u16*)(w + 16777216);     // 8192x256 bf16  ( 4 MB)
    float* sums = (float*)(w + 20971520);   // s1(512) + Etot(1) + pad + s2(512)
    float* sums2 = sums + 544;

    hipMemsetAsync(sums, 0, 1088 * sizeof(float), stream);

    pq_stats<<<256, 1024, 0, stream>>>(state, msg_w1, edges, msg_b1,
                                       PQb, EQf, sums);

    s_agg_h2_kernel<<<dim3(256, 2), 512, 0, stream>>>(
        PQb, edges, EQf, sums, msg_gamma, msg_beta, msg_b1,
        state, msg_w2, msg_b2, fin_w1, fin_b1, H2b, sums2);

    out_gemm<<<dim3(4, 128), 256, 0, stream>>>(
        H2b, fin_w2, fin_b2, sums2, fin_gamma, fin_beta, (float*)d_out);
}

// Round 10
// 82.634 us; speedup vs baseline: 1.8603x; 1.0036x over previous
//
#include <hip/hip_runtime.h>

#define NPAIR  262144
#define BN_EPS 1e-5f

typedef unsigned short u16;
typedef unsigned int   u32;
typedef __attribute__((ext_vector_type(8))) short bf16x8;
typedef __attribute__((ext_vector_type(4))) float f32x4;
typedef __attribute__((ext_vector_type(4))) unsigned short u16x4;
typedef __attribute__((ext_vector_type(4))) unsigned int u32x4;

__device__ __forceinline__ u16 f2bf(float f) {
    union { float f; unsigned u; } v; v.f = f;
    unsigned r = v.u + 0x7fffu + ((v.u >> 16) & 1u);
    return (u16)(r >> 16);
}
__device__ __forceinline__ float bf2f(u16 u) {
    union { unsigned u; float f; } v; v.u = ((unsigned)u) << 16; return v.f;
}
__device__ __forceinline__ bf16x8 cvt8_f32(const float* p) {
    f32x4 v0 = *(const f32x4*)p, v1 = *(const f32x4*)(p + 4);
    bf16x8 r;
    #pragma unroll
    for (int k = 0; k < 4; ++k) {
        r[k]     = (short)f2bf(v0[k]);
        r[4 + k] = (short)f2bf(v1[k]);
    }
    return r;
}
// bf16 input + BN + lrelu -> bf16 fragment
__device__ __forceinline__ bf16x8 cvt8_bn_b(const u16* p, const float* a, const float* d) {
    u16x4 v0 = *(const u16x4*)p, v1 = *(const u16x4*)(p + 4);
    f32x4 a0 = *(const f32x4*)a, a1 = *(const f32x4*)(a + 4);
    f32x4 d0 = *(const f32x4*)d, d1 = *(const f32x4*)(d + 4);
    bf16x8 r;
    #pragma unroll
    for (int k = 0; k < 4; ++k) {
        float x0 = fmaf(a0[k], bf2f(v0[k]), d0[k]); x0 = fmaxf(x0, 0.01f * x0);
        float x1 = fmaf(a1[k], bf2f(v1[k]), d1[k]); x1 = fmaxf(x1, 0.01f * x1);
        r[k]     = (short)f2bf(x0);
        r[4 + k] = (short)f2bf(x1);
    }
    return r;
}

// ---------------------------------------------------------------------------
// micro zero kernel: the rocclr fillBuffer dispatch costs ~40 us of device
// time regardless of size (measured R1/R3/R9 profiles); this costs ~2 us.
// ---------------------------------------------------------------------------
__global__ __launch_bounds__(256) void zero_kernel(float* __restrict__ p)
{
    const int i = blockIdx.x * 256 + threadIdx.x;
    if (i < 1088) p[i] = 0.f;
}

// ---------------------------------------------------------------------------
// Per-batch fused kernel, 1024 threads (16 waves):
//   PQ[32x512] = state @ [w1a|w1b]^T (MFMA, 32 cols/wave, W1 cvt inline)
//   -> PQb bf16 ;  EQ_i = sum_{j:e=1} Q_j -> EQf ;  analytic BN1 moments.
// ---------------------------------------------------------------------------
__global__ __launch_bounds__(1024) void pq_stats(
    const float* __restrict__ state, const float* __restrict__ w1,
    const float* __restrict__ edges, const float* __restrict__ b1,
    u16* __restrict__ PQb, float* __restrict__ EQf,
    float* __restrict__ sums)
{
    __shared__ float Qls[33 * 256];                 // 33 KB rounded Q (row32=0)
    __shared__ float redA[16 * 256];                // 16 KB
    __shared__ float redB[16 * 256];                // 16 KB
    __shared__ u32 masks[32];
    __shared__ __align__(16) unsigned char list8[32 * 32];
    __shared__ float cdf[32];

    const int b    = blockIdx.x;
    const int t    = threadIdx.x;
    const int lane = t & 63;
    const int w    = t >> 6;       // 0..15
    const int lr   = lane & 15;
    const int lk   = (lane >> 4) * 8;
    const int c0   = lane * 4;

    if (t < 256) ((u32*)list8)[t] = 0x20202020u;    // pad sentinel j=32
    if (t < 64) { const f32x4 z = {}; *(f32x4*)&Qls[32 * 256 + t * 4] = z; }

    // one edge per thread (t = il*32 + j)
    const float ev = edges[(size_t)b * 1024 + t];

    // ---- GEMM: wave w covers cols w*32..w*32+31 (W1 converted inline) ----
    const int col0 = w * 32;
    f32x4 acc[2][2] = {};
    #pragma unroll
    for (int ks = 0; ks < 4; ++ks) {
        const int kabs = ks * 32 + lk;
        bf16x8 af[2];
        #pragma unroll
        for (int rf = 0; rf < 2; ++rf)
            af[rf] = cvt8_f32(state + (size_t)(b * 32 + rf * 16 + lr) * 128 + kabs);
        #pragma unroll
        for (int cf = 0; cf < 2; ++cf) {
            const int coln = col0 + cf * 16 + lr;
            const float* wp = (coln < 256) ? (w1 + (size_t)coln * 256 + kabs)
                                           : (w1 + (size_t)(coln - 256) * 256 + 128 + kabs);
            const bf16x8 bfr = cvt8_f32(wp);
            #pragma unroll
            for (int rf = 0; rf < 2; ++rf)
                acc[rf][cf] = __builtin_amdgcn_mfma_f32_16x16x32_bf16(af[rf], bfr, acc[rf][cf], 0, 0, 0);
        }
    }
    #pragma unroll
    for (int rf = 0; rf < 2; ++rf)
        #pragma unroll
        for (int cf = 0; cf < 2; ++cf) {
            const int col = col0 + cf * 16 + lr;
            #pragma unroll
            for (int r = 0; r < 4; ++r) {
                const int row = rf * 16 + (lane >> 4) * 4 + r;
                const u16 u = f2bf(acc[rf][cf][r]);
                PQb[(size_t)(b * 32 + row) * 512 + col] = u;
                if (col >= 256) Qls[row * 256 + (col - 256)] = bf2f(u);
            }
        }
    __syncthreads();   // S1: staging + inits visible

    // ---- masks + compacted lists ----
    {
        const int il_t = t >> 5;
        const int j_t  = t & 31;
        const unsigned long long bal = __ballot(ev != 0.f);
        const u32 m32 = (lane < 32) ? (u32)bal : (u32)(bal >> 32);
        if (ev != 0.f)
            list8[il_t * 32 + __popc(m32 & ((1u << j_t) - 1u))] = (unsigned char)j_t;
        if (j_t == 0) masks[il_t] = m32;
    }
    __syncthreads();   // S2: masks + lists ready

    if (t < 32) {
        u32 cnt = 0;
        #pragma unroll
        for (int i = 0; i < 32; ++i) cnt += (masks[i] >> t) & 1u;
        cdf[t] = (float)cnt;
    }
    if (t == 0) {
        int tot = 0;
        #pragma unroll
        for (int i = 0; i < 32; ++i) tot += __popc(masks[i]);
        atomicAdd(&sums[512], (float)tot);
    }

    const f32x4 b14 = *(const f32x4*)(b1 + c0);
    f32x4 sumA = {}, sumB = {};

    // ---- EQ + row-terms: wave w owns rows 2w, 2w+1 ----
    #pragma unroll
    for (int ii = 0; ii < 2; ++ii) {
        const int il = 2 * w + ii;
        const int n1 = __popc(masks[il]);
        const int npad = (n1 + 3) & ~3;
        const float frd = (float)n1;
        f32x4 eq = {};
        const u32x4 l0 = *(const u32x4*)(list8 + il * 32);
        const u32x4 l1 = *(const u32x4*)(list8 + il * 32 + 16);
        const u32 wbuf[8] = {l0[0], l0[1], l0[2], l0[3], l1[0], l1[1], l1[2], l1[3]};
        #pragma unroll
        for (int wi = 0; wi < 8; ++wi) {
            if (wi * 4 >= npad) break;
            const u32 w4 = wbuf[wi];
            #pragma unroll
            for (int kb = 0; kb < 4; ++kb) {
                const int j = (w4 >> (kb * 8)) & 0xff;          // pads -> row 32 (zero)
                const f32x4 q = *(const f32x4*)&Qls[j * 256 + c0];
                #pragma unroll
                for (int k = 0; k < 4; ++k) eq[k] += q[k];
            }
        }
        *(f32x4*)(EQf + (size_t)(b * 32 + il) * 256 + c0) = eq;
        const u16x4 pu = *(const u16x4*)(PQb + (size_t)(b * 32 + il) * 512 + c0);
        #pragma unroll
        for (int k = 0; k < 4; ++k) {
            const float pb = bf2f(pu[k]) + b14[k];
            sumA[k] += frd * pb + eq[k];
            sumB[k] = fmaf(frd * pb + 2.f * eq[k], pb, sumB[k]);
        }
    }
    __syncthreads();   // S3: cdf ready

    // ---- coldeg-weighted Q^2: wave w uses j = 2w, 2w+1 ----
    #pragma unroll
    for (int jj = 0; jj < 2; ++jj) {
        const int j = 2 * w + jj;
        const float cdj = cdf[j];
        const f32x4 q = *(const f32x4*)&Qls[j * 256 + c0];
        #pragma unroll
        for (int k = 0; k < 4; ++k) sumB[k] = fmaf(cdj * q[k], q[k], sumB[k]);
    }
    *(f32x4*)&redA[w * 256 + c0] = sumA;
    *(f32x4*)&redB[w * 256 + c0] = sumB;
    __syncthreads();   // S4
    if (t < 256) {
        float a = 0.f, bb = 0.f;
        #pragma unroll
        for (int ww = 0; ww < 16; ++ww) {
            a  += redA[ww * 256 + t];
            bb += redB[ww * 256 + t];
        }
        atomicAdd(&sums[t], a);
        atomicAdd(&sums[256 + t], bb);
    }
}

// ---------------------------------------------------------------------------
// S (abs-split) -> agg MFMA (LDS) -> H2 MFMA + BN2 stats, all batch-local.
// 512 threads (8 waves), 16 rows/block, grid (256, 2).
// ---------------------------------------------------------------------------
__global__ __launch_bounds__(512) void s_agg_h2_kernel(
    const u16* __restrict__ PQb, const float* __restrict__ edges,
    const float* __restrict__ EQf, const float* __restrict__ sums,
    const float* __restrict__ gamma, const float* __restrict__ beta,
    const float* __restrict__ b1, const float* __restrict__ state,
    const float* __restrict__ w2, const float* __restrict__ b2,
    const float* __restrict__ fw1, const float* __restrict__ fb1,
    u16* __restrict__ H2b, float* __restrict__ sums2)
{
    __shared__ float Qls[33 * 256];               // 33 KB a-scaled Q (row32=0)
    __shared__ u16 Ssb[16 * 256];                 // 8 KB, swizzled
    __shared__ u16 Asb[16 * 128];                 // 4 KB, swizzled (state bf16)
    __shared__ u16 aggs[16 * 128];                // 4 KB, swizzled
    __shared__ __align__(16) unsigned char list8[16 * 32];
    __shared__ int n1s[16];
    __shared__ float sred[512];

    const int b    = blockIdx.x;
    const int i0   = blockIdx.y * 16;
    const int t    = threadIdx.x;
    const int lane = t & 63;
    const int w    = t >> 6;      // 0..7
    const int lr   = lane & 15;
    const int lkg  = lane >> 4;   // 0..3
    const int lk   = lkg * 8;
    const int c0   = lane * 4;

    sred[t] = 0.f;

    // BN1 coefficients from analytic sums
    const float Etot = sums[512];
    const float nz   = (float)NPAIR - Etot;
    const float invN = 1.f / (float)NPAIR;
    const f32x4 s1  = *(const f32x4*)(sums + c0);
    const f32x4 s2  = *(const f32x4*)(sums + 256 + c0);
    const f32x4 g4  = *(const f32x4*)(gamma + c0);
    const f32x4 be4 = *(const f32x4*)(beta + c0);
    const f32x4 b14 = *(const f32x4*)(b1 + c0);
    f32x4 a4, d4, ld4;
    #pragma unroll
    for (int k = 0; k < 4; ++k) {
        const float mean = (s1[k] + nz * b14[k]) * invN;
        const float ms   = (s2[k] + nz * b14[k] * b14[k]) * invN;
        const float var  = fmaf(-mean, mean, ms);
        a4[k]  = g4[k] * rsqrtf(var + BN_EPS);
        d4[k]  = fmaf(b14[k] - mean, a4[k], be4[k]);
        ld4[k] = fmaxf(d4[k], 0.01f * d4[k]);
    }

    // stage a-scaled Q (f32): 8 waves x 4 iters = 32 rows
    #pragma unroll
    for (int it = 0; it < 4; ++it) {
        const int row = w + it * 8;
        const u16x4 qu = *(const u16x4*)(PQb + (size_t)(b * 32 + row) * 512 + 256 + c0);
        f32x4 q;
        #pragma unroll
        for (int k = 0; k < 4; ++k) q[k] = a4[k] * bf2f(qu[k]);
        *(f32x4*)&Qls[row * 256 + c0] = q;
    }
    // stage state rows (bf16, swizzled) for the H2 GEMM
    if (t < 256) {
        const int row = t >> 4, k8 = (t & 15) * 8;
        const bf16x8 av = cvt8_f32(state + (size_t)(b * 32 + i0 + row) * 128 + k8);
        *(bf16x8*)((char*)Asb + ((row * 256 + k8 * 2) ^ ((row & 7) << 4))) = av;
    }
    if (t < 64) { const f32x4 z = {}; *(f32x4*)&Qls[32 * 256 + t * 4] = z; }
    if (t < 128) ((u32*)list8)[t] = 0x20202020u;

    const float ev = edges[(size_t)b * 1024 + (i0 + (t >> 5)) * 32 + (t & 31)];
    __syncthreads();

    {
        const int il_t = t >> 5;
        const int j_t  = t & 31;
        const unsigned long long bal = __ballot(ev != 0.f);
        const u32 m32 = (lane < 32) ? (u32)bal : (u32)(bal >> 32);
        if (ev != 0.f)
            list8[il_t * 32 + __popc(m32 & ((1u << j_t) - 1u))] = (unsigned char)j_t;
        if (j_t == 0) n1s[il_t] = __popc(m32);
    }
    __syncthreads();

    // ---- S rows (abs-split), wave w owns rows 2w, 2w+1 ----
    #pragma unroll
    for (int ii = 0; ii < 2; ++ii) {
        const int il = 2 * w + ii;
        const int gi = b * 32 + i0 + il;
        const int n1 = n1s[il];
        const int npad = (n1 + 3) & ~3;
        const float frd = (float)n1;
        const float fz = (float)(32 - n1);
        const float fp = (float)(npad - n1);
        const u16x4 pu = *(const u16x4*)(PQb + (size_t)gi * 512 + c0);
        const f32x4 eq4 = *(const f32x4*)(EQf + (size_t)gi * 256 + c0);
        f32x4 ap, absacc;
        #pragma unroll
        for (int k = 0; k < 4; ++k) {
            ap[k] = fmaf(a4[k], bf2f(pu[k]), d4[k]);
            absacc[k] = -fp * fabsf(ap[k]);      // pad correction
        }
        const u32x4 l0 = *(const u32x4*)(list8 + il * 32);
        const u32x4 l1 = *(const u32x4*)(list8 + il * 32 + 16);
        const u32 wbuf[8] = {l0[0], l0[1], l0[2], l0[3], l1[0], l1[1], l1[2], l1[3]};
        #pragma unroll
        for (int wi = 0; wi < 8; ++wi) {
            if (wi * 4 >= npad) break;
            const u32 w4 = wbuf[wi];
            #pragma unroll
            for (int kb = 0; kb < 4; ++kb) {
                const int j = (w4 >> (kb * 8)) & 0xff;
                const f32x4 q = *(const f32x4*)&Qls[j * 256 + c0];
                #pragma unroll
                for (int k = 0; k < 4; ++k)
                    absacc[k] += fabsf(ap[k] + q[k]);
            }
        }
        u16x4 o;
        #pragma unroll
        for (int k = 0; k < 4; ++k) {
            const float lin = fmaf(frd, ap[k], a4[k] * eq4[k]);
            const float S = fmaf(fz, ld4[k], fmaf(0.505f, lin, 0.495f * absacc[k]));
            o[k] = f2bf(S);
        }
        *(u16x4*)((char*)Ssb + il * 512 + ((lane * 8) ^ ((il & 7) << 4))) = o;
    }
    __syncthreads();

    // ---- agg = S @ w2^T + 32*b2 -> aggs LDS (w2 cvt inline) ----
    {
        f32x4 acc2 = {};
        #pragma unroll
        for (int ks = 0; ks < 8; ++ks) {
            const int rdoff = (ks * 64 + lkg * 16) ^ ((lr & 7) << 4);
            const bf16x8 afr = *(const bf16x8*)((const char*)Ssb + lr * 512 + rdoff);
            const bf16x8 bfr = cvt8_f32(w2 + (size_t)(w * 16 + lr) * 256 + ks * 32 + lk);
            acc2 = __builtin_amdgcn_mfma_f32_16x16x32_bf16(afr, bfr, acc2, 0, 0, 0);
        }
        const int col = w * 16 + lr;
        const float bv = 32.f * b2[col];
        #pragma unroll
        for (int r = 0; r < 4; ++r) {
            const int row = lkg * 4 + r;
            *(u16*)((char*)aggs + ((row * 256 + col * 2) ^ ((row & 7) << 4))) = f2bf(acc2[r] + bv);
        }
    }
    __syncthreads();

    // ---- H2 = [Asb | aggs] @ fw1^T + fb1 -> H2b global + BN2 stats ----
    {
        f32x4 acc3[2] = {};
        #pragma unroll
        for (int ks = 0; ks < 8; ++ks) {
            const int kabs = ks * 32 + lk;
            const int row = lr;
            bf16x8 af3;
            if (ks < 4)
                af3 = *(const bf16x8*)((const char*)Asb + ((row * 256 + kabs * 2) ^ ((row & 7) << 4)));
            else
                af3 = *(const bf16x8*)((const char*)aggs + ((row * 256 + (kabs - 128) * 2) ^ ((row & 7) << 4)));
            #pragma unroll
            for (int cf = 0; cf < 2; ++cf) {
                const int col = w * 32 + cf * 16 + lr;
                const bf16x8 bfr = cvt8_f32(fw1 + (size_t)col * 256 + kabs);
                acc3[cf] = __builtin_amdgcn_mfma_f32_16x16x32_bf16(af3, bfr, acc3[cf], 0, 0, 0);
            }
        }
        #pragma unroll
        for (int cf = 0; cf < 2; ++cf) {
            const int col = w * 32 + cf * 16 + lr;
            const float bv = fb1[col];
            float s = 0.f, ss = 0.f;
            #pragma unroll
            for (int r = 0; r < 4; ++r) {
                const int row = lkg * 4 + r;
                const float v = acc3[cf][r] + bv;
                H2b[(size_t)(b * 32 + i0 + row) * 256 + col] = f2bf(v);
                s += v;
                ss = fmaf(v, v, ss);
            }
            atomicAdd(&sred[col], s);
            atomicAdd(&sred[256 + col], ss);
        }
    }
    __syncthreads();
    if (t < 256) {
        atomicAdd(&sums2[t], sred[t]);
        atomicAdd(&sums2[256 + t], sred[256 + t]);
    }
}

// ---------------------------------------------------------------------------
// out = lrelu(bn(H2b)) @ fw2^T + fb2, finalize2 in-block, fw2 cvt inline.
// ---------------------------------------------------------------------------
__global__ __launch_bounds__(256) void out_gemm(
    const u16* __restrict__ H2b, const float* __restrict__ fw2,
    const float* __restrict__ fb2, const float* __restrict__ sums2,
    const float* __restrict__ gamma, const float* __restrict__ beta,
    float* __restrict__ out)
{
    __shared__ float adl[512];
    const int t = threadIdx.x;
    {
        const float invR = 1.f / 8192.f;
        const float mean = sums2[t] * invR;
        const float var  = fmaf(-mean, mean, sums2[256 + t] * invR);
        const float a    = gamma[t] * rsqrtf(var + BN_EPS);
        adl[t]       = a;
        adl[256 + t] = fmaf(-mean, a, beta[t]);
    }
    __syncthreads();

    const int lane = t & 63;
    const int wave = t >> 6;
    const int row0 = blockIdx.y * 64 + wave * 16;
    const int col0 = blockIdx.x * 32;
    const int lr = lane & 15;
    const int lk = (lane >> 4) * 8;

    f32x4 acc[2] = {};
    #pragma unroll
    for (int ks = 0; ks < 8; ++ks) {
        const int kabs = ks * 32 + lk;
        const bf16x8 af = cvt8_bn_b(H2b + (size_t)(row0 + lr) * 256 + kabs,
                                    adl + kabs, adl + 256 + kabs);
        #pragma unroll
        for (int cf = 0; cf < 2; ++cf) {
            const bf16x8 bf = cvt8_f32(fw2 + (size_t)(col0 + cf * 16 + lr) * 256 + kabs);
            acc[cf] = __builtin_amdgcn_mfma_f32_16x16x32_bf16(af, bf, acc[cf], 0, 0, 0);
        }
    }
    #pragma unroll
    for (int cf = 0; cf < 2; ++cf) {
        const int col = col0 + cf * 16 + lr;
        const float bv = fb2[col];
        #pragma unroll
        for (int r = 0; r < 4; ++r) {
            const int row = row0 + (lane >> 4) * 4 + r;
            out[(size_t)row * 128 + col] = acc[cf][r] + bv;
        }
    }
}

// ---------------------------------------------------------------------------
extern "C" void kernel_launch(void* const* d_in, const int* in_sizes, int n_in,
                              void* d_out, int out_size, void* d_ws, size_t ws_size,
                              hipStream_t stream)
{
    const float* state     = (const float*)d_in[0];
    const float* edges     = (const float*)d_in[1];
    const float* msg_w1    = (const float*)d_in[2];
    const float* msg_b1    = (const float*)d_in[3];
    const float* msg_gamma = (const float*)d_in[4];
    const float* msg_beta  = (const float*)d_in[5];
    const float* msg_w2    = (const float*)d_in[6];
    const float* msg_b2    = (const float*)d_in[7];
    const float* fin_w1    = (const float*)d_in[8];
    const float* fin_b1    = (const float*)d_in[9];
    const float* fin_gamma = (const float*)d_in[10];
    const float* fin_beta  = (const float*)d_in[11];
    const float* fin_w2    = (const float*)d_in[12];
    const float* fin_b2    = (const float*)d_in[13];

    char* w = (char*)d_ws;
    u16*   PQb  = (u16*)(w);                // 8192x512 bf16  ( 8 MB)
    float* EQf  = (float*)(w + 8388608);    // 8192x256 f32   ( 8 MB)
    u16*   H2b  = (u16*)(w + 16777216);     // 8192x256 bf16  ( 4 MB)
    float* sums = (float*)(w + 20971520);   // s1(512) + Etot(1) + pad + s2(512)
    float* sums2 = sums + 544;

    zero_kernel<<<5, 256, 0, stream>>>(sums);

    pq_stats<<<256, 1024, 0, stream>>>(state, msg_w1, edges, msg_b1,
                                       PQb, EQf, sums);

    s_agg_h2_kernel<<<dim3(256, 2), 512, 0, stream>>>(
        PQb, edges, EQf, sums, msg_gamma, msg_beta, msg_b1,
        state, msg_w2, msg_b2, fin_w1, fin_b1, H2b, sums2);

    out_gemm<<<dim3(4, 128), 256, 0, stream>>>(
        H2b, fin_w2, fin_b2, sums2, fin_gamma, fin_beta, (float*)d_out);
}

// Round 11
// 68.490 us; speedup vs baseline: 2.2445x; 1.2065x over previous
//
#include <hip/hip_runtime.h>

#define NPAIR  262144
#define BN_EPS 1e-5f

typedef unsigned short u16;
typedef unsigned int   u32;
typedef __attribute__((ext_vector_type(8))) short bf16x8;
typedef __attribute__((ext_vector_type(4))) float f32x4;
typedef __attribute__((ext_vector_type(4))) unsigned short u16x4;
typedef __attribute__((ext_vector_type(4))) unsigned int u32x4;

__device__ __forceinline__ u16 f2bf(float f) {
    union { float f; unsigned u; } v; v.f = f;
    unsigned r = v.u + 0x7fffu + ((v.u >> 16) & 1u);
    return (u16)(r >> 16);
}
__device__ __forceinline__ float bf2f(u16 u) {
    union { unsigned u; float f; } v; v.u = ((unsigned)u) << 16; return v.f;
}
__device__ __forceinline__ u16x4 cvt4(float4 v) {
    u16x4 r;
    r[0] = f2bf(v.x); r[1] = f2bf(v.y); r[2] = f2bf(v.z); r[3] = f2bf(v.w);
    return r;
}
__device__ __forceinline__ bf16x8 cvt8_f32(const float* p) {
    f32x4 v0 = *(const f32x4*)p, v1 = *(const f32x4*)(p + 4);
    bf16x8 r;
    #pragma unroll
    for (int k = 0; k < 4; ++k) {
        r[k]     = (short)f2bf(v0[k]);
        r[4 + k] = (short)f2bf(v1[k]);
    }
    return r;
}
// bf16 input + BN + lrelu -> bf16 fragment
__device__ __forceinline__ bf16x8 cvt8_bn_b(const u16* p, const float* a, const float* d) {
    u16x4 v0 = *(const u16x4*)p, v1 = *(const u16x4*)(p + 4);
    f32x4 a0 = *(const f32x4*)a, a1 = *(const f32x4*)(a + 4);
    f32x4 d0 = *(const f32x4*)d, d1 = *(const f32x4*)(d + 4);
    bf16x8 r;
    #pragma unroll
    for (int k = 0; k < 4; ++k) {
        float x0 = fmaf(a0[k], bf2f(v0[k]), d0[k]); x0 = fmaxf(x0, 0.01f * x0);
        float x1 = fmaf(a1[k], bf2f(v1[k]), d1[k]); x1 = fmaxf(x1, 0.01f * x1);
        r[k]     = (short)f2bf(x0);
        r[4 + k] = (short)f2bf(x1);
    }
    return r;
}

// ---------------------------------------------------------------------------
// prep: weights fp32->bf16 once (W1b remapped [512][128]) + zero sums region.
// Pre-converting weights matters: inline f32 weight reads in MFMA loops
// cost 2x bytes + cvt VALU in the fragment-feed path (R9 regression, -13us).
// ---------------------------------------------------------------------------
__global__ __launch_bounds__(256) void prep_kernel(
    const float* __restrict__ w1, const float4* __restrict__ w2,
    const float4* __restrict__ fw1, const float4* __restrict__ fw2,
    u16x4* __restrict__ W1b, u16x4* __restrict__ W2b,
    u16x4* __restrict__ FW1b, u16x4* __restrict__ FW2b,
    f32x4* __restrict__ sums)
{
    int g = blockIdx.x * 256 + threadIdx.x;
    if (g < 16384) {
        const int o = g * 4, n = o >> 7, k = o & 127;
        const float4 v = *(const float4*)(w1 + (n < 256 ? n * 256 + k
                                                        : (n - 256) * 256 + 128 + k));
        W1b[g] = cvt4(v); return;
    }
    g -= 16384;
    if (g < 8192) { W2b[g] = cvt4(w2[g]); return; }
    g -= 8192;
    if (g < 16384) { FW1b[g] = cvt4(fw1[g]); return; }
    g -= 16384;
    if (g < 8192) { FW2b[g] = cvt4(fw2[g]); return; }
    g -= 8192;
    if (g < 264) { const f32x4 z = {}; sums[g] = z; }
}

// ---------------------------------------------------------------------------
// Per-batch fused kernel, 1024 threads (16 waves):
//   PQ[32x512] = state @ [w1a|w1b]^T (MFMA, 32 cols/wave) -> PQb bf16 (+Ab)
//   analytic BN1 moments (degree-weighted, EQ consumed in-register).
// ---------------------------------------------------------------------------
__global__ __launch_bounds__(1024) void pq_stats(
    const float* __restrict__ state, const u16* __restrict__ W1b,
    const float* __restrict__ edges, const float* __restrict__ b1,
    u16* __restrict__ PQb, u16* __restrict__ Ab,
    float* __restrict__ sums)
{
    __shared__ float Qls[33 * 256];                 // 33 KB rounded Q (row32=0)
    __shared__ float redA[16 * 256];                // 16 KB
    __shared__ float redB[16 * 256];                // 16 KB
    __shared__ u32 masks[32];
    __shared__ __align__(16) unsigned char list8[32 * 32];
    __shared__ float cdf[32];

    const int b    = blockIdx.x;
    const int t    = threadIdx.x;
    const int lane = t & 63;
    const int w    = t >> 6;       // 0..15
    const int lr   = lane & 15;
    const int lk   = (lane >> 4) * 8;
    const int c0   = lane * 4;

    if (t < 256) ((u32*)list8)[t] = 0x20202020u;    // pad sentinel j=32
    if (t < 64) { const f32x4 z = {}; *(f32x4*)&Qls[32 * 256 + t * 4] = z; }

    // one edge per thread (t = il*32 + j)
    const float ev = edges[(size_t)b * 1024 + t];

    // ---- GEMM: wave w covers cols w*32..w*32+31 ----
    const int col0 = w * 32;
    f32x4 acc[2][2] = {};
    #pragma unroll
    for (int ks = 0; ks < 4; ++ks) {
        const int kabs = ks * 32 + lk;
        bf16x8 af[2];
        #pragma unroll
        for (int rf = 0; rf < 2; ++rf)
            af[rf] = cvt8_f32(state + (size_t)(b * 32 + rf * 16 + lr) * 128 + kabs);
        if (w == 0) {
            #pragma unroll
            for (int rf = 0; rf < 2; ++rf)
                *(bf16x8*)(Ab + (size_t)(b * 32 + rf * 16 + lr) * 128 + kabs) = af[rf];
        }
        #pragma unroll
        for (int cf = 0; cf < 2; ++cf) {
            const bf16x8 bfr = *(const bf16x8*)(W1b + (size_t)(col0 + cf * 16 + lr) * 128 + kabs);
            #pragma unroll
            for (int rf = 0; rf < 2; ++rf)
                acc[rf][cf] = __builtin_amdgcn_mfma_f32_16x16x32_bf16(af[rf], bfr, acc[rf][cf], 0, 0, 0);
        }
    }
    #pragma unroll
    for (int rf = 0; rf < 2; ++rf)
        #pragma unroll
        for (int cf = 0; cf < 2; ++cf) {
            const int col = col0 + cf * 16 + lr;
            #pragma unroll
            for (int r = 0; r < 4; ++r) {
                const int row = rf * 16 + (lane >> 4) * 4 + r;
                const u16 u = f2bf(acc[rf][cf][r]);
                PQb[(size_t)(b * 32 + row) * 512 + col] = u;
                if (col >= 256) Qls[row * 256 + (col - 256)] = bf2f(u);
            }
        }
    __syncthreads();   // S1: staging + inits visible

    // ---- masks + compacted lists ----
    {
        const int il_t = t >> 5;
        const int j_t  = t & 31;
        const unsigned long long bal = __ballot(ev != 0.f);
        const u32 m32 = (lane < 32) ? (u32)bal : (u32)(bal >> 32);
        if (ev != 0.f)
            list8[il_t * 32 + __popc(m32 & ((1u << j_t) - 1u))] = (unsigned char)j_t;
        if (j_t == 0) masks[il_t] = m32;
    }
    __syncthreads();   // S2: masks + lists ready

    if (t < 32) {
        u32 cnt = 0;
        #pragma unroll
        for (int i = 0; i < 32; ++i) cnt += (masks[i] >> t) & 1u;
        cdf[t] = (float)cnt;
    }
    if (t == 0) {
        int tot = 0;
        #pragma unroll
        for (int i = 0; i < 32; ++i) tot += __popc(masks[i]);
        atomicAdd(&sums[512], (float)tot);
    }

    const f32x4 b14 = *(const f32x4*)(b1 + c0);
    f32x4 sumA = {}, sumB = {};

    // ---- EQ + row-terms: wave w owns rows 2w, 2w+1 ----
    #pragma unroll
    for (int ii = 0; ii < 2; ++ii) {
        const int il = 2 * w + ii;
        const int n1 = __popc(masks[il]);
        const int npad = (n1 + 3) & ~3;
        const float frd = (float)n1;
        f32x4 eq = {};
        const u32x4 l0 = *(const u32x4*)(list8 + il * 32);
        const u32x4 l1 = *(const u32x4*)(list8 + il * 32 + 16);
        const u32 wbuf[8] = {l0[0], l0[1], l0[2], l0[3], l1[0], l1[1], l1[2], l1[3]};
        #pragma unroll
        for (int wi = 0; wi < 8; ++wi) {
            if (wi * 4 >= npad) break;
            const u32 w4 = wbuf[wi];
            #pragma unroll
            for (int kb = 0; kb < 4; ++kb) {
                const int j = (w4 >> (kb * 8)) & 0xff;          // pads -> row 32 (zero)
                const f32x4 q = *(const f32x4*)&Qls[j * 256 + c0];
                #pragma unroll
                for (int k = 0; k < 4; ++k) eq[k] += q[k];
            }
        }
        const u16x4 pu = *(const u16x4*)(PQb + (size_t)(b * 32 + il) * 512 + c0);
        #pragma unroll
        for (int k = 0; k < 4; ++k) {
            const float pb = bf2f(pu[k]) + b14[k];
            sumA[k] += frd * pb + eq[k];
            sumB[k] = fmaf(frd * pb + 2.f * eq[k], pb, sumB[k]);
        }
    }
    __syncthreads();   // S3: cdf ready

    // ---- coldeg-weighted Q^2: wave w uses j = 2w, 2w+1 ----
    #pragma unroll
    for (int jj = 0; jj < 2; ++jj) {
        const int j = 2 * w + jj;
        const float cdj = cdf[j];
        const f32x4 q = *(const f32x4*)&Qls[j * 256 + c0];
        #pragma unroll
        for (int k = 0; k < 4; ++k) sumB[k] = fmaf(cdj * q[k], q[k], sumB[k]);
    }
    *(f32x4*)&redA[w * 256 + c0] = sumA;
    *(f32x4*)&redB[w * 256 + c0] = sumB;
    __syncthreads();   // S4
    if (t < 256) {
        float a = 0.f, bb = 0.f;
        #pragma unroll
        for (int ww = 0; ww < 16; ++ww) {
            a  += redA[ww * 256 + t];
            bb += redB[ww * 256 + t];
        }
        atomicAdd(&sums[t], a);
        atomicAdd(&sums[256 + t], bb);
    }
}

// ---------------------------------------------------------------------------
// S via abs-split + fused agg GEMM; 512 threads (8 waves), 16 rows/block.
// Linear term accumulated in the edge loop (linq) — no EQf round-trip.
// ---------------------------------------------------------------------------
__global__ __launch_bounds__(512) void s_agg_kernel(
    const u16* __restrict__ PQb, const float* __restrict__ edges,
    const float* __restrict__ sums, const float* __restrict__ gamma,
    const float* __restrict__ beta, const float* __restrict__ b1,
    const u16* __restrict__ W2b, const float* __restrict__ b2,
    u16* __restrict__ aggb)
{
    __shared__ float Qls[33 * 256];               // 33 KB a-scaled Q (row32=0)
    __shared__ u16 Ssb[16 * 256];                 // 8 KB, row-XOR swizzled
    __shared__ __align__(16) unsigned char list8[16 * 32];
    __shared__ int n1s[16];

    const int b    = blockIdx.x;
    const int i0   = blockIdx.y * 16;
    const int t    = threadIdx.x;
    const int lane = t & 63;
    const int w    = t >> 6;      // 0..7
    const int lr   = lane & 15;
    const int lkg  = lane >> 4;
    const int lk   = lkg * 8;
    const int c0   = lane * 4;

    // BN1 coefficients from analytic sums
    const float Etot = sums[512];
    const float nz   = (float)NPAIR - Etot;
    const float invN = 1.f / (float)NPAIR;
    const f32x4 s1  = *(const f32x4*)(sums + c0);
    const f32x4 s2  = *(const f32x4*)(sums + 256 + c0);
    const f32x4 g4  = *(const f32x4*)(gamma + c0);
    const f32x4 be4 = *(const f32x4*)(beta + c0);
    const f32x4 b14 = *(const f32x4*)(b1 + c0);
    f32x4 a4, d4, ld4;
    #pragma unroll
    for (int k = 0; k < 4; ++k) {
        const float mean = (s1[k] + nz * b14[k]) * invN;
        const float ms   = (s2[k] + nz * b14[k] * b14[k]) * invN;
        const float var  = fmaf(-mean, mean, ms);
        a4[k]  = g4[k] * rsqrtf(var + BN_EPS);
        d4[k]  = fmaf(b14[k] - mean, a4[k], be4[k]);
        ld4[k] = fmaxf(d4[k], 0.01f * d4[k]);
    }

    // stage a-scaled Q (f32): 8 waves x 4 iters = 32 rows
    #pragma unroll
    for (int it = 0; it < 4; ++it) {
        const int row = w + it * 8;
        const u16x4 qu = *(const u16x4*)(PQb + (size_t)(b * 32 + row) * 512 + 256 + c0);
        f32x4 q;
        #pragma unroll
        for (int k = 0; k < 4; ++k) q[k] = a4[k] * bf2f(qu[k]);
        *(f32x4*)&Qls[row * 256 + c0] = q;
    }
    if (t < 64) { const f32x4 z = {}; *(f32x4*)&Qls[32 * 256 + t * 4] = z; }
    if (t < 128) ((u32*)list8)[t] = 0x20202020u;

    const float ev = edges[(size_t)b * 1024 + (i0 + (t >> 5)) * 32 + (t & 31)];
    __syncthreads();

    {
        const int il_t = t >> 5;
        const int j_t  = t & 31;
        const unsigned long long bal = __ballot(ev != 0.f);
        const u32 m32 = (lane < 32) ? (u32)bal : (u32)(bal >> 32);
        if (ev != 0.f)
            list8[il_t * 32 + __popc(m32 & ((1u << j_t) - 1u))] = (unsigned char)j_t;
        if (j_t == 0) n1s[il_t] = __popc(m32);
    }
    __syncthreads();

    #pragma unroll
    for (int ii = 0; ii < 2; ++ii) {
        const int il = 2 * w + ii;
        const int gi = b * 32 + i0 + il;
        const int n1 = n1s[il];
        const int npad = (n1 + 3) & ~3;
        const float frd = (float)n1;
        const float fz = (float)(32 - n1);
        const float fp = (float)(npad - n1);
        const u16x4 pu = *(const u16x4*)(PQb + (size_t)gi * 512 + c0);
        f32x4 ap, absacc, linq = {};
        #pragma unroll
        for (int k = 0; k < 4; ++k) {
            ap[k] = fmaf(a4[k], bf2f(pu[k]), d4[k]);
            absacc[k] = -fp * fabsf(ap[k]);      // pad correction (pads add |ap|)
        }
        const u32x4 l0 = *(const u32x4*)(list8 + il * 32);
        const u32x4 l1 = *(const u32x4*)(list8 + il * 32 + 16);
        const u32 wbuf[8] = {l0[0], l0[1], l0[2], l0[3], l1[0], l1[1], l1[2], l1[3]};
        #pragma unroll
        for (int wi = 0; wi < 8; ++wi) {
            if (wi * 4 >= npad) break;
            const u32 w4 = wbuf[wi];
            #pragma unroll
            for (int kb = 0; kb < 4; ++kb) {
                const int j = (w4 >> (kb * 8)) & 0xff;
                const f32x4 q = *(const f32x4*)&Qls[j * 256 + c0];
                #pragma unroll
                for (int k = 0; k < 4; ++k) {
                    absacc[k] += fabsf(ap[k] + q[k]);
                    linq[k]   += q[k];           // pads add 0 (row 32 zeroed)
                }
            }
        }
        u16x4 o;
        #pragma unroll
        for (int k = 0; k < 4; ++k) {
            const float lin = fmaf(frd, ap[k], linq[k]);   // q already a-scaled
            const float S = fmaf(fz, ld4[k], fmaf(0.505f, lin, 0.495f * absacc[k]));
            o[k] = f2bf(S);
        }
        const int off = (lane * 8) ^ ((il & 7) << 4);
        *(u16x4*)((char*)Ssb + il * 512 + off) = o;
    }
    __syncthreads();

    // agg tail: agg[16x128] = S @ w2^T + 32*b2 ; wave w covers 16 cols
    const int colw = w * 16;
    f32x4 acc2 = {};
    #pragma unroll
    for (int ks = 0; ks < 8; ++ks) {
        const int rdoff = (ks * 64 + lkg * 16) ^ ((lr & 7) << 4);
        const bf16x8 afr = *(const bf16x8*)((const char*)Ssb + lr * 512 + rdoff);
        const bf16x8 bfr = *(const bf16x8*)(W2b + (size_t)(colw + lr) * 256 + ks * 32 + lk);
        acc2 = __builtin_amdgcn_mfma_f32_16x16x32_bf16(afr, bfr, acc2, 0, 0, 0);
    }
    {
        const int col = colw + lr;
        const float bv = 32.f * b2[col];
        #pragma unroll
        for (int r = 0; r < 4; ++r) {
            const int rowl = lkg * 4 + r;
            aggb[(size_t)(b * 32 + i0 + rowl) * 128 + col] = f2bf(acc2[r] + bv);
        }
    }
}

// ---------------------------------------------------------------------------
// H2 = [Ab | aggb] @ fw1^T + fb1 -> bf16 + fused column stats.
// ---------------------------------------------------------------------------
__global__ __launch_bounds__(256) void h2_gemm(
    const u16* __restrict__ Ab, const u16* __restrict__ aggb,
    const u16* __restrict__ FW1b, const float* __restrict__ fb1,
    u16* __restrict__ H2b, float* __restrict__ sums2)
{
    __shared__ float sred[64];
    const int lane = threadIdx.x & 63;
    const int wave = threadIdx.x >> 6;
    const int row0 = blockIdx.y * 64 + wave * 16;
    const int col0 = blockIdx.x * 32;
    const int lr = lane & 15;
    const int lk = (lane >> 4) * 8;

    f32x4 acc[2] = {};
    #pragma unroll
    for (int ks = 0; ks < 8; ++ks) {
        const int kabs = ks * 32 + lk;
        const bf16x8 af = (kabs < 128)
            ? *(const bf16x8*)(Ab   + (size_t)(row0 + lr) * 128 + kabs)
            : *(const bf16x8*)(aggb + (size_t)(row0 + lr) * 128 + (kabs - 128));
        #pragma unroll
        for (int cf = 0; cf < 2; ++cf) {
            const bf16x8 bf = *(const bf16x8*)(FW1b + (size_t)(col0 + cf * 16 + lr) * 256 + kabs);
            acc[cf] = __builtin_amdgcn_mfma_f32_16x16x32_bf16(af, bf, acc[cf], 0, 0, 0);
        }
    }

    if (threadIdx.x < 64) sred[threadIdx.x] = 0.f;
    __syncthreads();
    #pragma unroll
    for (int cf = 0; cf < 2; ++cf) {
        const int col = col0 + cf * 16 + lr;
        const float bv = fb1[col];
        float s = 0.f, ss = 0.f;
        #pragma unroll
        for (int r = 0; r < 4; ++r) {
            const int row = row0 + (lane >> 4) * 4 + r;
            const float v = acc[cf][r] + bv;
            H2b[(size_t)row * 256 + col] = f2bf(v);
            s += v;
            ss = fmaf(v, v, ss);
        }
        atomicAdd(&sred[cf * 16 + lr], s);
        atomicAdd(&sred[32 + cf * 16 + lr], ss);
    }
    __syncthreads();
    if (threadIdx.x < 32) {
        atomicAdd(&sums2[col0 + threadIdx.x], sred[threadIdx.x]);
        atomicAdd(&sums2[256 + col0 + threadIdx.x], sred[32 + threadIdx.x]);
    }
}

// ---------------------------------------------------------------------------
// out = lrelu(bn(H2b)) @ fw2^T + fb2, finalize2 computed in-block.
// ---------------------------------------------------------------------------
__global__ __launch_bounds__(256) void out_gemm(
    const u16* __restrict__ H2b, const u16* __restrict__ FW2b,
    const float* __restrict__ fb2, const float* __restrict__ sums2,
    const float* __restrict__ gamma, const float* __restrict__ beta,
    float* __restrict__ out)
{
    __shared__ float adl[512];
    const int t = threadIdx.x;
    {
        const float invR = 1.f / 8192.f;
        const float mean = sums2[t] * invR;
        const float var  = fmaf(-mean, mean, sums2[256 + t] * invR);
        const float a    = gamma[t] * rsqrtf(var + BN_EPS);
        adl[t]       = a;
        adl[256 + t] = fmaf(-mean, a, beta[t]);
    }
    __syncthreads();

    const int lane = t & 63;
    const int wave = t >> 6;
    const int row0 = blockIdx.y * 64 + wave * 16;
    const int col0 = blockIdx.x * 32;
    const int lr = lane & 15;
    const int lk = (lane >> 4) * 8;

    f32x4 acc[2] = {};
    #pragma unroll
    for (int ks = 0; ks < 8; ++ks) {
        const int kabs = ks * 32 + lk;
        const bf16x8 af = cvt8_bn_b(H2b + (size_t)(row0 + lr) * 256 + kabs,
                                    adl + kabs, adl + 256 + kabs);
        #pragma unroll
        for (int cf = 0; cf < 2; ++cf) {
            const bf16x8 bf = *(const bf16x8*)(FW2b + (size_t)(col0 + cf * 16 + lr) * 256 + kabs);
            acc[cf] = __builtin_amdgcn_mfma_f32_16x16x32_bf16(af, bf, acc[cf], 0, 0, 0);
        }
    }
    #pragma unroll
    for (int cf = 0; cf < 2; ++cf) {
        const int col = col0 + cf * 16 + lr;
        const float bv = fb2[col];
        #pragma unroll
        for (int r = 0; r < 4; ++r) {
            const int row = row0 + (lane >> 4) * 4 + r;
            out[(size_t)row * 128 + col] = acc[cf][r] + bv;
        }
    }
}

// ---------------------------------------------------------------------------
extern "C" void kernel_launch(void* const* d_in, const int* in_sizes, int n_in,
                              void* d_out, int out_size, void* d_ws, size_t ws_size,
                              hipStream_t stream)
{
    const float* state     = (const float*)d_in[0];
    const float* edges     = (const float*)d_in[1];
    const float* msg_w1    = (const float*)d_in[2];
    const float* msg_b1    = (const float*)d_in[3];
    const float* msg_gamma = (const float*)d_in[4];
    const float* msg_beta  = (const float*)d_in[5];
    const float* msg_w2    = (const float*)d_in[6];
    const float* msg_b2    = (const float*)d_in[7];
    const float* fin_w1    = (const float*)d_in[8];
    const float* fin_b1    = (const float*)d_in[9];
    const float* fin_gamma = (const float*)d_in[10];
    const float* fin_beta  = (const float*)d_in[11];
    const float* fin_w2    = (const float*)d_in[12];
    const float* fin_b2    = (const float*)d_in[13];

    char* w = (char*)d_ws;
    u16*   PQb  = (u16*)(w);                // 8192x512 bf16  ( 8 MB)
    u16*   Ab   = (u16*)(w + 8388608);      // 8192x128 bf16  ( 2 MB)
    u16*   aggb = (u16*)(w + 10485760);     // 8192x128 bf16  ( 2 MB)
    u16*   H2b  = (u16*)(w + 12582912);     // 8192x256 bf16  ( 4 MB)
    u16*   W1b  = (u16*)(w + 16777216);     // [512][128] bf16
    u16*   W2b  = (u16*)(w + 16908288);     // [128][256] bf16
    u16*   FW1b = (u16*)(w + 16973824);     // [256][256] bf16
    u16*   FW2b = (u16*)(w + 17104896);     // [128][256] bf16
    float* sums = (float*)(w + 17170432);   // s1(512)+Etot(1)+pad(31)+s2(512)
    float* sums2 = sums + 544;

    prep_kernel<<<194, 256, 0, stream>>>(
        msg_w1, (const float4*)msg_w2, (const float4*)fin_w1, (const float4*)fin_w2,
        (u16x4*)W1b, (u16x4*)W2b, (u16x4*)FW1b, (u16x4*)FW2b, (f32x4*)sums);

    pq_stats<<<256, 1024, 0, stream>>>(state, W1b, edges, msg_b1,
                                       PQb, Ab, sums);

    s_agg_kernel<<<dim3(256, 2), 512, 0, stream>>>(
        PQb, edges, sums, msg_gamma, msg_beta, msg_b1, W2b, msg_b2, aggb);

    h2_gemm<<<dim3(8, 128), 256, 0, stream>>>(Ab, aggb, FW1b, fin_b1, H2b, sums2);

    out_gemm<<<dim3(4, 128), 256, 0, stream>>>(
        H2b, FW2b, fin_b2, sums2, fin_gamma, fin_beta, (float*)d_out);
}

// Round 12
// 66.490 us; speedup vs baseline: 2.3121x; 1.0301x over previous
//
#include <hip/hip_runtime.h>

#define NPAIR  262144
#define BN_EPS 1e-5f

typedef unsigned short u16;
typedef unsigned int   u32;
typedef __attribute__((ext_vector_type(8))) short bf16x8;
typedef __attribute__((ext_vector_type(4))) float f32x4;
typedef __attribute__((ext_vector_type(4))) unsigned short u16x4;
typedef __attribute__((ext_vector_type(4))) unsigned int u32x4;

__device__ __forceinline__ u16 f2bf(float f) {
    union { float f; unsigned u; } v; v.f = f;
    unsigned r = v.u + 0x7fffu + ((v.u >> 16) & 1u);
    return (u16)(r >> 16);
}
__device__ __forceinline__ float bf2f(u16 u) {
    union { unsigned u; float f; } v; v.u = ((unsigned)u) << 16; return v.f;
}
__device__ __forceinline__ u16x4 cvt4(float4 v) {
    u16x4 r;
    r[0] = f2bf(v.x); r[1] = f2bf(v.y); r[2] = f2bf(v.z); r[3] = f2bf(v.w);
    return r;
}
__device__ __forceinline__ bf16x8 cvt8_f32(const float* p) {
    f32x4 v0 = *(const f32x4*)p, v1 = *(const f32x4*)(p + 4);
    bf16x8 r;
    #pragma unroll
    for (int k = 0; k < 4; ++k) {
        r[k]     = (short)f2bf(v0[k]);
        r[4 + k] = (short)f2bf(v1[k]);
    }
    return r;
}
// bf16 input + BN + lrelu -> bf16 fragment
__device__ __forceinline__ bf16x8 cvt8_bn_b(const u16* p, const float* a, const float* d) {
    u16x4 v0 = *(const u16x4*)p, v1 = *(const u16x4*)(p + 4);
    f32x4 a0 = *(const f32x4*)a, a1 = *(const f32x4*)(a + 4);
    f32x4 d0 = *(const f32x4*)d, d1 = *(const f32x4*)(d + 4);
    bf16x8 r;
    #pragma unroll
    for (int k = 0; k < 4; ++k) {
        float x0 = fmaf(a0[k], bf2f(v0[k]), d0[k]); x0 = fmaxf(x0, 0.01f * x0);
        float x1 = fmaf(a1[k], bf2f(v1[k]), d1[k]); x1 = fmaxf(x1, 0.01f * x1);
        r[k]     = (short)f2bf(x0);
        r[4 + k] = (short)f2bf(x1);
    }
    return r;
}

// ---------------------------------------------------------------------------
// prep: weights fp32->bf16 once (W1b remapped [512][128]) + zero sums region.
// Pre-converting weights matters: inline f32 weight reads in MFMA loops
// cost 2x bytes + cvt VALU in the fragment-feed path (R9 regression).
// ---------------------------------------------------------------------------
__global__ __launch_bounds__(256) void prep_kernel(
    const float* __restrict__ w1, const float4* __restrict__ w2,
    const float4* __restrict__ fw1, const float4* __restrict__ fw2,
    u16x4* __restrict__ W1b, u16x4* __restrict__ W2b,
    u16x4* __restrict__ FW1b, u16x4* __restrict__ FW2b,
    f32x4* __restrict__ sums)
{
    int g = blockIdx.x * 256 + threadIdx.x;
    if (g < 16384) {
        const int o = g * 4, n = o >> 7, k = o & 127;
        const float4 v = *(const float4*)(w1 + (n < 256 ? n * 256 + k
                                                        : (n - 256) * 256 + 128 + k));
        W1b[g] = cvt4(v); return;
    }
    g -= 16384;
    if (g < 8192) { W2b[g] = cvt4(w2[g]); return; }
    g -= 8192;
    if (g < 16384) { FW1b[g] = cvt4(fw1[g]); return; }
    g -= 16384;
    if (g < 8192) { FW2b[g] = cvt4(fw2[g]); return; }
    g -= 8192;
    if (g < 264) { const f32x4 z = {}; sums[g] = z; }
}

// ---------------------------------------------------------------------------
// Per-batch fused kernel, 1024 threads (16 waves):
//   PQ[32x512] = state @ [w1a|w1b]^T (MFMA, 32 cols/wave) -> PQb bf16
//   analytic BN1 moments (degree-weighted, EQ consumed in-register).
// ---------------------------------------------------------------------------
__global__ __launch_bounds__(1024) void pq_stats(
    const float* __restrict__ state, const u16* __restrict__ W1b,
    const float* __restrict__ edges, const float* __restrict__ b1,
    u16* __restrict__ PQb, float* __restrict__ sums)
{
    __shared__ float Qls[33 * 256];                 // 33 KB rounded Q (row32=0)
    __shared__ float redA[16 * 256];                // 16 KB
    __shared__ float redB[16 * 256];                // 16 KB
    __shared__ u32 masks[32];
    __shared__ __align__(16) unsigned char list8[32 * 32];
    __shared__ float cdf[32];

    const int b    = blockIdx.x;
    const int t    = threadIdx.x;
    const int lane = t & 63;
    const int w    = t >> 6;       // 0..15
    const int lr   = lane & 15;
    const int lk   = (lane >> 4) * 8;
    const int c0   = lane * 4;

    if (t < 256) ((u32*)list8)[t] = 0x20202020u;    // pad sentinel j=32
    if (t < 64) { const f32x4 z = {}; *(f32x4*)&Qls[32 * 256 + t * 4] = z; }

    // one edge per thread (t = il*32 + j)
    const float ev = edges[(size_t)b * 1024 + t];

    // ---- GEMM: wave w covers cols w*32..w*32+31 ----
    const int col0 = w * 32;
    f32x4 acc[2][2] = {};
    #pragma unroll
    for (int ks = 0; ks < 4; ++ks) {
        const int kabs = ks * 32 + lk;
        bf16x8 af[2];
        #pragma unroll
        for (int rf = 0; rf < 2; ++rf)
            af[rf] = cvt8_f32(state + (size_t)(b * 32 + rf * 16 + lr) * 128 + kabs);
        #pragma unroll
        for (int cf = 0; cf < 2; ++cf) {
            const bf16x8 bfr = *(const bf16x8*)(W1b + (size_t)(col0 + cf * 16 + lr) * 128 + kabs);
            #pragma unroll
            for (int rf = 0; rf < 2; ++rf)
                acc[rf][cf] = __builtin_amdgcn_mfma_f32_16x16x32_bf16(af[rf], bfr, acc[rf][cf], 0, 0, 0);
        }
    }
    #pragma unroll
    for (int rf = 0; rf < 2; ++rf)
        #pragma unroll
        for (int cf = 0; cf < 2; ++cf) {
            const int col = col0 + cf * 16 + lr;
            #pragma unroll
            for (int r = 0; r < 4; ++r) {
                const int row = rf * 16 + (lane >> 4) * 4 + r;
                const u16 u = f2bf(acc[rf][cf][r]);
                PQb[(size_t)(b * 32 + row) * 512 + col] = u;
                if (col >= 256) Qls[row * 256 + (col - 256)] = bf2f(u);
            }
        }
    __syncthreads();   // S1: staging + inits visible

    // ---- masks + compacted lists ----
    {
        const int il_t = t >> 5;
        const int j_t  = t & 31;
        const unsigned long long bal = __ballot(ev != 0.f);
        const u32 m32 = (lane < 32) ? (u32)bal : (u32)(bal >> 32);
        if (ev != 0.f)
            list8[il_t * 32 + __popc(m32 & ((1u << j_t) - 1u))] = (unsigned char)j_t;
        if (j_t == 0) masks[il_t] = m32;
    }
    __syncthreads();   // S2: masks + lists ready

    if (t < 32) {
        u32 cnt = 0;
        #pragma unroll
        for (int i = 0; i < 32; ++i) cnt += (masks[i] >> t) & 1u;
        cdf[t] = (float)cnt;
    }
    if (t == 0) {
        int tot = 0;
        #pragma unroll
        for (int i = 0; i < 32; ++i) tot += __popc(masks[i]);
        atomicAdd(&sums[512], (float)tot);
    }

    const f32x4 b14 = *(const f32x4*)(b1 + c0);
    f32x4 sumA = {}, sumB = {};

    // ---- EQ + row-terms: wave w owns rows 2w, 2w+1 ----
    #pragma unroll
    for (int ii = 0; ii < 2; ++ii) {
        const int il = 2 * w + ii;
        const int n1 = __popc(masks[il]);
        const int npad = (n1 + 3) & ~3;
        const float frd = (float)n1;
        f32x4 eq = {};
        const u32x4 l0 = *(const u32x4*)(list8 + il * 32);
        const u32x4 l1 = *(const u32x4*)(list8 + il * 32 + 16);
        const u32 wbuf[8] = {l0[0], l0[1], l0[2], l0[3], l1[0], l1[1], l1[2], l1[3]};
        #pragma unroll
        for (int wi = 0; wi < 8; ++wi) {
            if (wi * 4 >= npad) break;
            const u32 w4 = wbuf[wi];
            #pragma unroll
            for (int kb = 0; kb < 4; ++kb) {
                const int j = (w4 >> (kb * 8)) & 0xff;          // pads -> row 32 (zero)
                const f32x4 q = *(const f32x4*)&Qls[j * 256 + c0];
                #pragma unroll
                for (int k = 0; k < 4; ++k) eq[k] += q[k];
            }
        }
        const u16x4 pu = *(const u16x4*)(PQb + (size_t)(b * 32 + il) * 512 + c0);
        #pragma unroll
        for (int k = 0; k < 4; ++k) {
            const float pb = bf2f(pu[k]) + b14[k];
            sumA[k] += frd * pb + eq[k];
            sumB[k] = fmaf(frd * pb + 2.f * eq[k], pb, sumB[k]);
        }
    }
    __syncthreads();   // S3: cdf ready

    // ---- coldeg-weighted Q^2: wave w uses j = 2w, 2w+1 ----
    #pragma unroll
    for (int jj = 0; jj < 2; ++jj) {
        const int j = 2 * w + jj;
        const float cdj = cdf[j];
        const f32x4 q = *(const f32x4*)&Qls[j * 256 + c0];
        #pragma unroll
        for (int k = 0; k < 4; ++k) sumB[k] = fmaf(cdj * q[k], q[k], sumB[k]);
    }
    *(f32x4*)&redA[w * 256 + c0] = sumA;
    *(f32x4*)&redB[w * 256 + c0] = sumB;
    __syncthreads();   // S4
    if (t < 256) {
        float a = 0.f, bb = 0.f;
        #pragma unroll
        for (int ww = 0; ww < 16; ++ww) {
            a  += redA[ww * 256 + t];
            bb += redB[ww * 256 + t];
        }
        atomicAdd(&sums[t], a);
        atomicAdd(&sums[256 + t], bb);
    }
}

// ---------------------------------------------------------------------------
// S (abs-split) -> agg MFMA (LDS) -> H2 MFMA + BN2 stats, all batch-local.
// 512 threads (8 waves), 16 rows/block, grid (256, 2). Weights PRE-CONVERTED
// (bf16) — R9's regression came from inline f32 weight reads, not the merge.
// ---------------------------------------------------------------------------
__global__ __launch_bounds__(512) void s_agg_h2_kernel(
    const u16* __restrict__ PQb, const float* __restrict__ edges,
    const float* __restrict__ sums, const float* __restrict__ gamma,
    const float* __restrict__ beta, const float* __restrict__ b1,
    const float* __restrict__ state,
    const u16* __restrict__ W2b, const float* __restrict__ b2,
    const u16* __restrict__ FW1b, const float* __restrict__ fb1,
    u16* __restrict__ H2b, float* __restrict__ sums2)
{
    __shared__ float Qls[33 * 256];               // 33 KB a-scaled Q (row32=0)
    __shared__ u16 Ssb[16 * 256];                 // 8 KB, swizzled
    __shared__ u16 Asb[16 * 128];                 // 4 KB, swizzled (state bf16)
    __shared__ u16 aggs[16 * 128];                // 4 KB, swizzled
    __shared__ __align__(16) unsigned char list8[16 * 32];
    __shared__ int n1s[16];
    __shared__ float sred[512];

    const int b    = blockIdx.x;
    const int i0   = blockIdx.y * 16;
    const int t    = threadIdx.x;
    const int lane = t & 63;
    const int w    = t >> 6;      // 0..7
    const int lr   = lane & 15;
    const int lkg  = lane >> 4;   // 0..3
    const int lk   = lkg * 8;
    const int c0   = lane * 4;

    sred[t] = 0.f;

    // BN1 coefficients from analytic sums
    const float Etot = sums[512];
    const float nz   = (float)NPAIR - Etot;
    const float invN = 1.f / (float)NPAIR;
    const f32x4 s1  = *(const f32x4*)(sums + c0);
    const f32x4 s2  = *(const f32x4*)(sums + 256 + c0);
    const f32x4 g4  = *(const f32x4*)(gamma + c0);
    const f32x4 be4 = *(const f32x4*)(beta + c0);
    const f32x4 b14 = *(const f32x4*)(b1 + c0);
    f32x4 a4, d4, ld4;
    #pragma unroll
    for (int k = 0; k < 4; ++k) {
        const float mean = (s1[k] + nz * b14[k]) * invN;
        const float ms   = (s2[k] + nz * b14[k] * b14[k]) * invN;
        const float var  = fmaf(-mean, mean, ms);
        a4[k]  = g4[k] * rsqrtf(var + BN_EPS);
        d4[k]  = fmaf(b14[k] - mean, a4[k], be4[k]);
        ld4[k] = fmaxf(d4[k], 0.01f * d4[k]);
    }

    // stage a-scaled Q (f32): 8 waves x 4 iters = 32 rows
    #pragma unroll
    for (int it = 0; it < 4; ++it) {
        const int row = w + it * 8;
        const u16x4 qu = *(const u16x4*)(PQb + (size_t)(b * 32 + row) * 512 + 256 + c0);
        f32x4 q;
        #pragma unroll
        for (int k = 0; k < 4; ++k) q[k] = a4[k] * bf2f(qu[k]);
        *(f32x4*)&Qls[row * 256 + c0] = q;
    }
    // stage state rows (bf16, swizzled) for the H2 GEMM
    if (t < 256) {
        const int row = t >> 4, k8 = (t & 15) * 8;
        const bf16x8 av = cvt8_f32(state + (size_t)(b * 32 + i0 + row) * 128 + k8);
        *(bf16x8*)((char*)Asb + ((row * 256 + k8 * 2) ^ ((row & 7) << 4))) = av;
    }
    if (t < 64) { const f32x4 z = {}; *(f32x4*)&Qls[32 * 256 + t * 4] = z; }
    if (t < 128) ((u32*)list8)[t] = 0x20202020u;

    const float ev = edges[(size_t)b * 1024 + (i0 + (t >> 5)) * 32 + (t & 31)];
    __syncthreads();

    {
        const int il_t = t >> 5;
        const int j_t  = t & 31;
        const unsigned long long bal = __ballot(ev != 0.f);
        const u32 m32 = (lane < 32) ? (u32)bal : (u32)(bal >> 32);
        if (ev != 0.f)
            list8[il_t * 32 + __popc(m32 & ((1u << j_t) - 1u))] = (unsigned char)j_t;
        if (j_t == 0) n1s[il_t] = __popc(m32);
    }
    __syncthreads();

    // ---- S rows (abs-split + in-loop linear term), wave w owns rows 2w,2w+1
    #pragma unroll
    for (int ii = 0; ii < 2; ++ii) {
        const int il = 2 * w + ii;
        const int gi = b * 32 + i0 + il;
        const int n1 = n1s[il];
        const int npad = (n1 + 3) & ~3;
        const float frd = (float)n1;
        const float fz = (float)(32 - n1);
        const float fp = (float)(npad - n1);
        const u16x4 pu = *(const u16x4*)(PQb + (size_t)gi * 512 + c0);
        f32x4 ap, absacc, linq = {};
        #pragma unroll
        for (int k = 0; k < 4; ++k) {
            ap[k] = fmaf(a4[k], bf2f(pu[k]), d4[k]);
            absacc[k] = -fp * fabsf(ap[k]);      // pad correction (pads add |ap|)
        }
        const u32x4 l0 = *(const u32x4*)(list8 + il * 32);
        const u32x4 l1 = *(const u32x4*)(list8 + il * 32 + 16);
        const u32 wbuf[8] = {l0[0], l0[1], l0[2], l0[3], l1[0], l1[1], l1[2], l1[3]};
        #pragma unroll
        for (int wi = 0; wi < 8; ++wi) {
            if (wi * 4 >= npad) break;
            const u32 w4 = wbuf[wi];
            #pragma unroll
            for (int kb = 0; kb < 4; ++kb) {
                const int j = (w4 >> (kb * 8)) & 0xff;
                const f32x4 q = *(const f32x4*)&Qls[j * 256 + c0];
                #pragma unroll
                for (int k = 0; k < 4; ++k) {
                    absacc[k] += fabsf(ap[k] + q[k]);
                    linq[k]   += q[k];           // pads add 0 (row 32 zeroed)
                }
            }
        }
        u16x4 o;
        #pragma unroll
        for (int k = 0; k < 4; ++k) {
            const float lin = fmaf(frd, ap[k], linq[k]);   // q already a-scaled
            const float S = fmaf(fz, ld4[k], fmaf(0.505f, lin, 0.495f * absacc[k]));
            o[k] = f2bf(S);
        }
        *(u16x4*)((char*)Ssb + il * 512 + ((lane * 8) ^ ((il & 7) << 4))) = o;
    }
    __syncthreads();

    // ---- agg = S @ w2^T + 32*b2 -> aggs LDS (bf16 weights) ----
    {
        f32x4 acc2 = {};
        #pragma unroll
        for (int ks = 0; ks < 8; ++ks) {
            const int rdoff = (ks * 64 + lkg * 16) ^ ((lr & 7) << 4);
            const bf16x8 afr = *(const bf16x8*)((const char*)Ssb + lr * 512 + rdoff);
            const bf16x8 bfr = *(const bf16x8*)(W2b + (size_t)(w * 16 + lr) * 256 + ks * 32 + lk);
            acc2 = __builtin_amdgcn_mfma_f32_16x16x32_bf16(afr, bfr, acc2, 0, 0, 0);
        }
        const int col = w * 16 + lr;
        const float bv = 32.f * b2[col];
        #pragma unroll
        for (int r = 0; r < 4; ++r) {
            const int row = lkg * 4 + r;
            *(u16*)((char*)aggs + ((row * 256 + col * 2) ^ ((row & 7) << 4))) = f2bf(acc2[r] + bv);
        }
    }
    __syncthreads();

    // ---- H2 = [Asb | aggs] @ fw1^T + fb1 -> H2b global + BN2 stats ----
    {
        f32x4 acc3[2] = {};
        #pragma unroll
        for (int ks = 0; ks < 8; ++ks) {
            const int kabs = ks * 32 + lk;
            const int row = lr;
            bf16x8 af3;
            if (ks < 4)
                af3 = *(const bf16x8*)((const char*)Asb + ((row * 256 + kabs * 2) ^ ((row & 7) << 4)));
            else
                af3 = *(const bf16x8*)((const char*)aggs + ((row * 256 + (kabs - 128) * 2) ^ ((row & 7) << 4)));
            #pragma unroll
            for (int cf = 0; cf < 2; ++cf) {
                const int col = w * 32 + cf * 16 + lr;
                const bf16x8 bfr = *(const bf16x8*)(FW1b + (size_t)col * 256 + kabs);
                acc3[cf] = __builtin_amdgcn_mfma_f32_16x16x32_bf16(af3, bfr, acc3[cf], 0, 0, 0);
            }
        }
        #pragma unroll
        for (int cf = 0; cf < 2; ++cf) {
            const int col = w * 32 + cf * 16 + lr;
            const float bv = fb1[col];
            float s = 0.f, ss = 0.f;
            #pragma unroll
            for (int r = 0; r < 4; ++r) {
                const int row = lkg * 4 + r;
                const float v = acc3[cf][r] + bv;
                H2b[(size_t)(b * 32 + i0 + row) * 256 + col] = f2bf(v);
                s += v;
                ss = fmaf(v, v, ss);
            }
            atomicAdd(&sred[col], s);
            atomicAdd(&sred[256 + col], ss);
        }
    }
    __syncthreads();
    if (t < 256) {
        atomicAdd(&sums2[t], sred[t]);
        atomicAdd(&sums2[256 + t], sred[256 + t]);
    }
}

// ---------------------------------------------------------------------------
// out = lrelu(bn(H2b)) @ fw2^T + fb2, finalize2 computed in-block.
// ---------------------------------------------------------------------------
__global__ __launch_bounds__(256) void out_gemm(
    const u16* __restrict__ H2b, const u16* __restrict__ FW2b,
    const float* __restrict__ fb2, const float* __restrict__ sums2,
    const float* __restrict__ gamma, const float* __restrict__ beta,
    float* __restrict__ out)
{
    __shared__ float adl[512];
    const int t = threadIdx.x;
    {
        const float invR = 1.f / 8192.f;
        const float mean = sums2[t] * invR;
        const float var  = fmaf(-mean, mean, sums2[256 + t] * invR);
        const float a    = gamma[t] * rsqrtf(var + BN_EPS);
        adl[t]       = a;
        adl[256 + t] = fmaf(-mean, a, beta[t]);
    }
    __syncthreads();

    const int lane = t & 63;
    const int wave = t >> 6;
    const int row0 = blockIdx.y * 64 + wave * 16;
    const int col0 = blockIdx.x * 32;
    const int lr = lane & 15;
    const int lk = (lane >> 4) * 8;

    f32x4 acc[2] = {};
    #pragma unroll
    for (int ks = 0; ks < 8; ++ks) {
        const int kabs = ks * 32 + lk;
        const bf16x8 af = cvt8_bn_b(H2b + (size_t)(row0 + lr) * 256 + kabs,
                                    adl + kabs, adl + 256 + kabs);
        #pragma unroll
        for (int cf = 0; cf < 2; ++cf) {
            const bf16x8 bf = *(const bf16x8*)(FW2b + (size_t)(col0 + cf * 16 + lr) * 256 + kabs);
            acc[cf] = __builtin_amdgcn_mfma_f32_16x16x32_bf16(af, bf, acc[cf], 0, 0, 0);
        }
    }
    #pragma unroll
    for (int cf = 0; cf < 2; ++cf) {
        const int col = col0 + cf * 16 + lr;
        const float bv = fb2[col];
        #pragma unroll
        for (int r = 0; r < 4; ++r) {
            const int row = row0 + (lane >> 4) * 4 + r;
            out[(size_t)row * 128 + col] = acc[cf][r] + bv;
        }
    }
}

// ---------------------------------------------------------------------------
extern "C" void kernel_launch(void* const* d_in, const int* in_sizes, int n_in,
                              void* d_out, int out_size, void* d_ws, size_t ws_size,
                              hipStream_t stream)
{
    const float* state     = (const float*)d_in[0];
    const float* edges     = (const float*)d_in[1];
    const float* msg_w1    = (const float*)d_in[2];
    const float* msg_b1    = (const float*)d_in[3];
    const float* msg_gamma = (const float*)d_in[4];
    const float* msg_beta  = (const float*)d_in[5];
    const float* msg_w2    = (const float*)d_in[6];
    const float* msg_b2    = (const float*)d_in[7];
    const float* fin_w1    = (const float*)d_in[8];
    const float* fin_b1    = (const float*)d_in[9];
    const float* fin_gamma = (const float*)d_in[10];
    const float* fin_beta  = (const float*)d_in[11];
    const float* fin_w2    = (const float*)d_in[12];
    const float* fin_b2    = (const float*)d_in[13];

    char* w = (char*)d_ws;
    u16*   PQb  = (u16*)(w);                // 8192x512 bf16  ( 8 MB)
    u16*   H2b  = (u16*)(w + 8388608);      // 8192x256 bf16  ( 4 MB)
    u16*   W1b  = (u16*)(w + 12582912);     // [512][128] bf16
    u16*   W2b  = (u16*)(w + 12713984);     // [128][256] bf16
    u16*   FW1b = (u16*)(w + 12779520);     // [256][256] bf16
    u16*   FW2b = (u16*)(w + 12910592);     // [128][256] bf16
    float* sums = (float*)(w + 12976128);   // s1(512)+Etot(1)+pad(31)+s2(512)
    float* sums2 = sums + 544;

    prep_kernel<<<194, 256, 0, stream>>>(
        msg_w1, (const float4*)msg_w2, (const float4*)fin_w1, (const float4*)fin_w2,
        (u16x4*)W1b, (u16x4*)W2b, (u16x4*)FW1b, (u16x4*)FW2b, (f32x4*)sums);

    pq_stats<<<256, 1024, 0, stream>>>(state, W1b, edges, msg_b1, PQb, sums);

    s_agg_h2_kernel<<<dim3(256, 2), 512, 0, stream>>>(
        PQb, edges, sums, msg_gamma, msg_beta, msg_b1,
        state, W2b, msg_b2, FW1b, fin_b1, H2b, sums2);

    out_gemm<<<dim3(4, 128), 256, 0, stream>>>(
        H2b, FW2b, fin_b2, sums2, fin_gamma, fin_beta, (float*)d_out);
}